// Round 1
// baseline (344.589 us; speedup 1.0000x reference)
//
#include <hip/hip_runtime.h>

typedef unsigned long long ull;

#define NC 10000   // H*W cells
#define D_ 256     // input dim
#define B_ 1024    // batch
#define W_ 100     // grid width

// monotonic float -> sortable uint mapping
__device__ __forceinline__ unsigned fkey(float f) {
    unsigned u = __float_as_uint(f);
    return (u & 0x80000000u) ? ~u : (u | 0x80000000u);
}

__device__ __forceinline__ void decay_params(const int* ep, const int* tp, float& lr, float& inv2r2) {
    double decay = 1.0 - (double)(*ep) / (double)(*tp);
    lr = (float)(0.5 * decay);                 // INIT_LR * decay
    float radius = (float)(50.0 * decay);      // INIT_RADIUS * decay
    inv2r2 = 1.0f / (2.0f * radius * radius);
}

__global__ void k_init(ull* bmu) {
    int i = blockIdx.x * 256 + threadIdx.x;
    if (i < B_) bmu[i] = ~0ull;
}

// one wave per cell: wnorm[c] = sum_d w[c][d]^2
__global__ __launch_bounds__(256) void k_wnorm(const float* __restrict__ w, float* __restrict__ wnorm) {
    int cell = blockIdx.x * 4 + (threadIdx.x >> 6);
    int lane = threadIdx.x & 63;
    float4 v = *reinterpret_cast<const float4*>(&w[(size_t)cell * D_ + lane * 4]);
    float s = v.x * v.x + v.y * v.y + v.z * v.z + v.w * v.w;
    #pragma unroll
    for (int off = 32; off; off >>= 1) s += __shfl_xor(s, off);
    if (lane == 0) wnorm[cell] = s;
}

// scores GEMM + fused argmin: score[b][c] = wnorm[c] - 2 * x[b].w[c]
// tile 128(b) x 128(c), BK=32, 8x8 per thread
__global__ __launch_bounds__(256) void k_scores(const float* __restrict__ x, const float* __restrict__ w,
                                                const float* __restrict__ wnorm, ull* __restrict__ bmu) {
    __shared__ __align__(16) char smraw[2 * 32 * 132 * 4];
    float (*As)[132] = reinterpret_cast<float(*)[132]>(smraw);
    float (*Bs)[132] = reinterpret_cast<float(*)[132]>(smraw + 32 * 132 * 4);
    ull (*red)[17] = reinterpret_cast<ull(*)[17]>(smraw);  // reused after compute

    const int tid = threadIdx.x;
    const int b0 = blockIdx.x * 128;
    const int c0 = blockIdx.y * 128;
    const int tx = tid & 15, ty = tid >> 4;

    float acc[8][8];
    #pragma unroll
    for (int i = 0; i < 8; ++i)
        #pragma unroll
        for (int j = 0; j < 8; ++j) acc[i][j] = 0.f;

    for (int k0 = 0; k0 < D_; k0 += 32) {
        if (k0) __syncthreads();
        #pragma unroll
        for (int j = 0; j < 4; ++j) {
            int f = tid + j * 256;          // [0,1024): 128 rows x 8 float4
            int m = f >> 3, kq = f & 7;
            float4 va = *reinterpret_cast<const float4*>(&x[(size_t)(b0 + m) * D_ + k0 + kq * 4]);
            As[kq * 4 + 0][m] = va.x; As[kq * 4 + 1][m] = va.y;
            As[kq * 4 + 2][m] = va.z; As[kq * 4 + 3][m] = va.w;
            int c = c0 + m; if (c >= NC) c = NC - 1;
            float4 vb = *reinterpret_cast<const float4*>(&w[(size_t)c * D_ + k0 + kq * 4]);
            Bs[kq * 4 + 0][m] = vb.x; Bs[kq * 4 + 1][m] = vb.y;
            Bs[kq * 4 + 2][m] = vb.z; Bs[kq * 4 + 3][m] = vb.w;
        }
        __syncthreads();
        #pragma unroll
        for (int k = 0; k < 32; ++k) {
            float af[8], bf[8];
            *reinterpret_cast<float4*>(&af[0]) = *reinterpret_cast<const float4*>(&As[k][ty * 4]);
            *reinterpret_cast<float4*>(&af[4]) = *reinterpret_cast<const float4*>(&As[k][64 + ty * 4]);
            *reinterpret_cast<float4*>(&bf[0]) = *reinterpret_cast<const float4*>(&Bs[k][tx * 4]);
            *reinterpret_cast<float4*>(&bf[4]) = *reinterpret_cast<const float4*>(&Bs[k][64 + tx * 4]);
            #pragma unroll
            for (int i = 0; i < 8; ++i)
                #pragma unroll
                for (int j = 0; j < 8; ++j)
                    acc[i][j] = fmaf(af[i], bf[j], acc[i][j]);
        }
    }
    __syncthreads();

    float wn[8];
    #pragma unroll
    for (int j = 0; j < 8; ++j) {
        int c = c0 + ((j < 4) ? tx * 4 + j : 64 + tx * 4 + (j - 4));
        wn[j] = (c < NC) ? wnorm[c] : __builtin_inff();
    }
    #pragma unroll
    for (int i = 0; i < 8; ++i) {
        int m = (i < 4) ? ty * 4 + i : 64 + ty * 4 + (i - 4);
        ull best = ~0ull;
        #pragma unroll
        for (int j = 0; j < 8; ++j) {
            int c = c0 + ((j < 4) ? tx * 4 + j : 64 + tx * 4 + (j - 4));
            float s = wn[j] - 2.0f * acc[i][j];
            ull p = ((ull)fkey(s) << 32) | (unsigned)c;
            best = p < best ? p : best;
        }
        red[m][tx] = best;
    }
    __syncthreads();
    if (tid < 128) {
        ull best = red[tid][0];
        #pragma unroll
        for (int j = 1; j < 16; ++j) { ull v = red[tid][j]; best = v < best ? v : best; }
        atomicMin(&bmu[b0 + tid], best);
    }
}

// per-cell suffix-product scan: coef[i][c] = a_i * prod_{j>i}(1-a_j); T[c] = prod_i(1-a_i)
__global__ __launch_bounds__(256) void k_scan(const ull* __restrict__ bmu, const int* __restrict__ ep,
                                              const int* __restrict__ tp, float* __restrict__ coef,
                                              float* __restrict__ T) {
    int c = blockIdx.x * 256 + threadIdx.x;
    if (c >= NC) return;
    int cy = c / W_, cx = c % W_;
    float lr, inv2r2;
    decay_params(ep, tp, lr, inv2r2);
    float s = 1.0f;
    for (int i = B_ - 1; i >= 0; --i) {
        int idx = (int)(unsigned)(bmu[i] & 0xffffffffull);
        int by = idx / W_, bx = idx % W_;
        float dy = (float)(by - cy), dx = (float)(bx - cx);
        float a = lr * __expf(-(dy * dy + dx * dx) * inv2r2);
        coef[(size_t)i * NC + c] = a * s;
        s *= (1.0f - a);
    }
    T[c] = s;
}

// update GEMM: out[c][d] = T[c]*w0[c][d] + sum_i coef[i][c]*x[i][d]
// tile 128(c) x 128(d), BK=32, 8x8 per thread; coef and x are both K-major
__global__ __launch_bounds__(256) void k_update(const float* __restrict__ coef, const float* __restrict__ x,
                                                const float* __restrict__ T, const float* __restrict__ w0,
                                                float* __restrict__ out) {
    __shared__ __align__(16) float As[32][132];
    __shared__ __align__(16) float Bs[32][132];
    const int tid = threadIdx.x;
    const int c0 = blockIdx.x * 128;
    const int n0 = blockIdx.y * 128;
    const int tx = tid & 15, ty = tid >> 4;

    float acc[8][8];
    #pragma unroll
    for (int i = 0; i < 8; ++i)
        #pragma unroll
        for (int j = 0; j < 8; ++j) acc[i][j] = 0.f;

    for (int k0 = 0; k0 < B_; k0 += 32) {
        if (k0) __syncthreads();
        #pragma unroll
        for (int j = 0; j < 4; ++j) {
            int f = tid + j * 256;          // [0,1024): 32 k x 32 float4
            int k = f >> 5, mq = f & 31;
            int cc = c0 + mq * 4; if (cc > NC - 4) cc = NC - 4;
            *reinterpret_cast<float4*>(&As[k][mq * 4]) =
                *reinterpret_cast<const float4*>(&coef[(size_t)(k0 + k) * NC + cc]);
            *reinterpret_cast<float4*>(&Bs[k][mq * 4]) =
                *reinterpret_cast<const float4*>(&x[(size_t)(k0 + k) * D_ + n0 + mq * 4]);
        }
        __syncthreads();
        #pragma unroll
        for (int k = 0; k < 32; ++k) {
            float af[8], bf[8];
            *reinterpret_cast<float4*>(&af[0]) = *reinterpret_cast<const float4*>(&As[k][ty * 4]);
            *reinterpret_cast<float4*>(&af[4]) = *reinterpret_cast<const float4*>(&As[k][64 + ty * 4]);
            *reinterpret_cast<float4*>(&bf[0]) = *reinterpret_cast<const float4*>(&Bs[k][tx * 4]);
            *reinterpret_cast<float4*>(&bf[4]) = *reinterpret_cast<const float4*>(&Bs[k][64 + tx * 4]);
            #pragma unroll
            for (int i = 0; i < 8; ++i)
                #pragma unroll
                for (int j = 0; j < 8; ++j)
                    acc[i][j] = fmaf(af[i], bf[j], acc[i][j]);
        }
    }

    #pragma unroll
    for (int i = 0; i < 8; ++i) {
        int c = c0 + ((i < 4) ? ty * 4 + i : 64 + ty * 4 + (i - 4));
        if (c < NC) {
            float t = T[c];
            {
                int d = n0 + tx * 4;
                float4 w4 = *reinterpret_cast<const float4*>(&w0[(size_t)c * D_ + d]);
                float4 o;
                o.x = fmaf(t, w4.x, acc[i][0]); o.y = fmaf(t, w4.y, acc[i][1]);
                o.z = fmaf(t, w4.z, acc[i][2]); o.w = fmaf(t, w4.w, acc[i][3]);
                *reinterpret_cast<float4*>(&out[(size_t)c * D_ + d]) = o;
            }
            {
                int d = n0 + 64 + tx * 4;
                float4 w4 = *reinterpret_cast<const float4*>(&w0[(size_t)c * D_ + d]);
                float4 o;
                o.x = fmaf(t, w4.x, acc[i][4]); o.y = fmaf(t, w4.y, acc[i][5]);
                o.z = fmaf(t, w4.z, acc[i][6]); o.w = fmaf(t, w4.w, acc[i][7]);
                *reinterpret_cast<float4*>(&out[(size_t)c * D_ + d]) = o;
            }
        }
    }
}

// fallback if ws is too small for coef: direct forward recurrence, block per cell
__global__ __launch_bounds__(256) void k_update_fallback(const float* __restrict__ x, const float* __restrict__ w0,
                                                         const ull* __restrict__ bmu, const int* ep, const int* tp,
                                                         float* __restrict__ out) {
    int c = blockIdx.x;
    int d = threadIdx.x;
    int cy = c / W_, cx = c % W_;
    float lr, inv2r2;
    decay_params(ep, tp, lr, inv2r2);
    float acc = w0[(size_t)c * D_ + d];
    for (int i = 0; i < B_; ++i) {
        int idx = (int)(unsigned)(bmu[i] & 0xffffffffull);
        int by = idx / W_, bx = idx % W_;
        float dy = (float)(by - cy), dx = (float)(bx - cx);
        float a = lr * __expf(-(dy * dy + dx * dx) * inv2r2);
        acc = fmaf(a, x[(size_t)i * D_ + d] - acc, acc);
    }
    out[(size_t)c * D_ + d] = acc;
}

extern "C" void kernel_launch(void* const* d_in, const int* in_sizes, int n_in,
                              void* d_out, int out_size, void* d_ws, size_t ws_size,
                              hipStream_t stream) {
    const float* x = (const float*)d_in[0];
    const float* w = (const float*)d_in[1];
    const int* ep = (const int*)d_in[2];
    const int* tp = (const int*)d_in[3];
    float* out = (float*)d_out;

    char* ws = (char*)d_ws;
    ull* bmu = (ull*)ws;                         // 1024 * 8B          @ 0
    float* T = (float*)(ws + 8192);              // 10000 * 4B         @ 8K
    float* wnorm = (float*)(ws + 49152);         // 10000 * 4B         @ 48K
    float* coef = (float*)(ws + 131072);         // 1024*10000*4B      @ 128K
    size_t required = 131072 + (size_t)B_ * NC * 4;

    k_init<<<4, 256, 0, stream>>>(bmu);
    k_wnorm<<<NC / 4, 256, 0, stream>>>(w, wnorm);
    k_scores<<<dim3(B_ / 128, (NC + 127) / 128), 256, 0, stream>>>(x, w, wnorm, bmu);
    if (ws_size >= required) {
        k_scan<<<(NC + 255) / 256, 256, 0, stream>>>(bmu, ep, tp, coef, T);
        k_update<<<dim3((NC + 127) / 128, D_ / 128), 256, 0, stream>>>(coef, x, T, w, out);
    } else {
        k_update_fallback<<<NC, 256, 0, stream>>>(x, w, bmu, ep, tp, out);
    }
}

// Round 2
// 155.811 us; speedup vs baseline: 2.2116x; 2.2116x over previous
//
#include <hip/hip_runtime.h>

typedef unsigned long long ull;
typedef unsigned short ushort_t;
typedef short bf16x8 __attribute__((ext_vector_type(8)));
typedef float f32x4 __attribute__((ext_vector_type(4)));

#define NC 10000   // H*W cells
#define D_ 256     // input dim
#define B_ 1024    // batch
#define W_ 100     // grid width

// monotonic float -> sortable uint mapping
__device__ __forceinline__ unsigned fkey(float f) {
    unsigned u = __float_as_uint(f);
    return (u & 0x80000000u) ? ~u : (u | 0x80000000u);
}

// exact RNE float -> bf16 bits (finite values)
__device__ __forceinline__ ushort_t f2bf(float f) {
    unsigned u = __float_as_uint(f);
    unsigned r = (u + 0x7fffu + ((u >> 16) & 1u)) >> 16;
    return (ushort_t)r;
}

__device__ __forceinline__ void decay_params(const int* ep, const int* tp, float& lr, float& inv2r2) {
    double decay = 1.0 - (double)(*ep) / (double)(*tp);
    lr = (float)(0.5 * decay);                 // INIT_LR * decay
    float radius = (float)(50.0 * decay);      // INIT_RADIUS * decay
    inv2r2 = 1.0f / (2.0f * radius * radius);
}

__global__ void k_init(ull* bmu) {
    int i = blockIdx.x * 256 + threadIdx.x;
    if (i < B_) bmu[i] = ~0ull;
}

// one wave per cell: wnorm[c] = sum_d w[c][d]^2
__global__ __launch_bounds__(256) void k_wnorm(const float* __restrict__ w, float* __restrict__ wnorm) {
    int cell = blockIdx.x * 4 + (threadIdx.x >> 6);
    int lane = threadIdx.x & 63;
    float4 v = *reinterpret_cast<const float4*>(&w[(size_t)cell * D_ + lane * 4]);
    float s = v.x * v.x + v.y * v.y + v.z * v.z + v.w * v.w;
    #pragma unroll
    for (int off = 32; off; off >>= 1) s += __shfl_xor(s, off);
    if (lane == 0) wnorm[cell] = s;
}

// scores GEMM + fused argmin: score[b][c] = wnorm[c] - 2 * x[b].w[c]   (fp32, unchanged)
__global__ __launch_bounds__(256) void k_scores(const float* __restrict__ x, const float* __restrict__ w,
                                                const float* __restrict__ wnorm, ull* __restrict__ bmu) {
    __shared__ __align__(16) char smraw[2 * 32 * 132 * 4];
    float (*As)[132] = reinterpret_cast<float(*)[132]>(smraw);
    float (*Bs)[132] = reinterpret_cast<float(*)[132]>(smraw + 32 * 132 * 4);
    ull (*red)[17] = reinterpret_cast<ull(*)[17]>(smraw);  // reused after compute

    const int tid = threadIdx.x;
    const int b0 = blockIdx.x * 128;
    const int c0 = blockIdx.y * 128;
    const int tx = tid & 15, ty = tid >> 4;

    float acc[8][8];
    #pragma unroll
    for (int i = 0; i < 8; ++i)
        #pragma unroll
        for (int j = 0; j < 8; ++j) acc[i][j] = 0.f;

    for (int k0 = 0; k0 < D_; k0 += 32) {
        if (k0) __syncthreads();
        #pragma unroll
        for (int j = 0; j < 4; ++j) {
            int f = tid + j * 256;          // [0,1024): 128 rows x 8 float4
            int m = f >> 3, kq = f & 7;
            float4 va = *reinterpret_cast<const float4*>(&x[(size_t)(b0 + m) * D_ + k0 + kq * 4]);
            As[kq * 4 + 0][m] = va.x; As[kq * 4 + 1][m] = va.y;
            As[kq * 4 + 2][m] = va.z; As[kq * 4 + 3][m] = va.w;
            int c = c0 + m; if (c >= NC) c = NC - 1;
            float4 vb = *reinterpret_cast<const float4*>(&w[(size_t)c * D_ + k0 + kq * 4]);
            Bs[kq * 4 + 0][m] = vb.x; Bs[kq * 4 + 1][m] = vb.y;
            Bs[kq * 4 + 2][m] = vb.z; Bs[kq * 4 + 3][m] = vb.w;
        }
        __syncthreads();
        #pragma unroll
        for (int k = 0; k < 32; ++k) {
            float af[8], bf[8];
            *reinterpret_cast<float4*>(&af[0]) = *reinterpret_cast<const float4*>(&As[k][ty * 4]);
            *reinterpret_cast<float4*>(&af[4]) = *reinterpret_cast<const float4*>(&As[k][64 + ty * 4]);
            *reinterpret_cast<float4*>(&bf[0]) = *reinterpret_cast<const float4*>(&Bs[k][tx * 4]);
            *reinterpret_cast<float4*>(&bf[4]) = *reinterpret_cast<const float4*>(&Bs[k][64 + tx * 4]);
            #pragma unroll
            for (int i = 0; i < 8; ++i)
                #pragma unroll
                for (int j = 0; j < 8; ++j)
                    acc[i][j] = fmaf(af[i], bf[j], acc[i][j]);
        }
    }
    __syncthreads();

    float wn[8];
    #pragma unroll
    for (int j = 0; j < 8; ++j) {
        int c = c0 + ((j < 4) ? tx * 4 + j : 64 + tx * 4 + (j - 4));
        wn[j] = (c < NC) ? wnorm[c] : __builtin_inff();
    }
    #pragma unroll
    for (int i = 0; i < 8; ++i) {
        int m = (i < 4) ? ty * 4 + i : 64 + ty * 4 + (i - 4);
        ull best = ~0ull;
        #pragma unroll
        for (int j = 0; j < 8; ++j) {
            int c = c0 + ((j < 4) ? tx * 4 + j : 64 + tx * 4 + (j - 4));
            float s = wn[j] - 2.0f * acc[i][j];
            ull p = ((ull)fkey(s) << 32) | (unsigned)c;
            best = p < best ? p : best;
        }
        red[m][tx] = best;
    }
    __syncthreads();
    if (tid < 128) {
        ull best = red[tid][0];
        #pragma unroll
        for (int j = 1; j < 16; ++j) { ull v = red[tid][j]; best = v < best ? v : best; }
        atomicMin(&bmu[b0 + tid], best);
    }
}

// decode BMU -> (by, bx) floats once
__global__ void k_decode(const ull* __restrict__ bmu, float2* __restrict__ xy) {
    int i = blockIdx.x * 256 + threadIdx.x;
    if (i < B_) {
        int idx = (int)(unsigned)(bmu[i] & 0xffffffffull);
        xy[i] = make_float2((float)(idx / W_), (float)(idx % W_));
    }
}

// x (1024 x 256 f32, k-major) -> xT (256 x 1024 bf16, d-major)
__global__ __launch_bounds__(256) void k_xT(const float* __restrict__ x, ushort_t* __restrict__ xT) {
    __shared__ ushort_t tile[64][65];
    int k0 = blockIdx.x * 64, d0 = blockIdx.y * 64;
    int tid = threadIdx.x;
    #pragma unroll
    for (int r = 0; r < 16; ++r) {
        int idx = r * 256 + tid;
        int i = idx >> 6, j = idx & 63;       // i = k-local, j = d-local
        tile[j][i] = f2bf(x[(size_t)(k0 + i) * D_ + d0 + j]);
    }
    __syncthreads();
    #pragma unroll
    for (int r = 0; r < 2; ++r) {
        int f = r * 256 + tid;                // [0,512): 64 d-rows x 8 units
        int row = f >> 3, u = f & 7;
        ushort_t v[8];
        #pragma unroll
        for (int e = 0; e < 8; ++e) v[e] = tile[row][u * 8 + e];
        *reinterpret_cast<uint4*>(&xT[(size_t)(d0 + row) * B_ + k0 + u * 8]) =
            *reinterpret_cast<uint4*>(v);
    }
}

// chunked 2-pass suffix scan: 8 threads per cell, 128 samples each.
// coefT[c][i] (bf16, c-major) = a_i * prod_{j>i}(1-a_j);  T[c] = prod_i(1-a_i)
__global__ __launch_bounds__(256) void k_scan(const float2* __restrict__ xy, const int* __restrict__ ep,
                                              const int* __restrict__ tp, ushort_t* __restrict__ coefT,
                                              float* __restrict__ T) {
    int g = blockIdx.x * 256 + threadIdx.x;
    int c = g >> 3, t = g & 7;
    if (c >= NC) return;                      // uniform per 8-lane group
    float cyf = (float)(c / W_), cxf = (float)(c % W_);
    float lr, inv2r2;
    decay_params(ep, tp, lr, inv2r2);
    int base = t * 128;

    // pass 1: chunk product P_t = prod_{i in chunk}(1 - a_i)
    float P = 1.0f;
    for (int i = base; i < base + 128; ++i) {
        float2 p = xy[i];
        float dy = p.x - cyf, dx = p.y - cxf;
        float a = lr * __expf(-(dy * dy + dx * dx) * inv2r2);
        P *= (1.0f - a);
    }
    // M_t = prod_{t' > t} P_{t'} via shfl within the 8-lane group
    int gbase = (threadIdx.x & 63) & ~7;
    float M = 1.0f;
    #pragma unroll
    for (int k = 1; k < 8; ++k) {
        float pk = __shfl(P, gbase + k, 64);
        if (k > t) M *= pk;
    }
    if (t == 0) T[c] = M * P;

    // pass 2: descending, coef[i] = a_i * s,  s = M * prod_{j>i, j in chunk}(1-a_j)
    float s = M;
    for (int seg = 15; seg >= 0; --seg) {
        ushort_t buf[8];
        #pragma unroll
        for (int e = 7; e >= 0; --e) {
            int i = base + seg * 8 + e;
            float2 p = xy[i];
            float dy = p.x - cyf, dx = p.y - cxf;
            float a = lr * __expf(-(dy * dy + dx * dx) * inv2r2);
            buf[e] = f2bf(a * s);
            s *= (1.0f - a);
        }
        *reinterpret_cast<uint4*>(&coefT[(size_t)c * B_ + base + seg * 8]) =
            *reinterpret_cast<uint4*>(buf);
    }
}

// update GEMM via bf16 MFMA: out[c][d] = T[c]*w0[c][d] + sum_k coefT[c][k]*xT[d][k]
// 64x64 tile, BK=64, 4 waves (2x2), each wave 32x32 via 2x2 16x16x32 frags.
// LDS [64][64] bf16 with 16B-unit XOR swizzle (unit ^= row&7) on write AND read.
__global__ __launch_bounds__(256) void k_update(const ushort_t* __restrict__ coefT, const ushort_t* __restrict__ xT,
                                                const float* __restrict__ T, const float* __restrict__ w0,
                                                float* __restrict__ out) {
    __shared__ __align__(16) ushort_t As[64 * 64];
    __shared__ __align__(16) ushort_t Bs[64 * 64];
    const int tid = threadIdx.x;
    const int c0 = blockIdx.x * 64, d0 = blockIdx.y * 64;
    const int wid = tid >> 6, lane = tid & 63;
    const int wc = wid >> 1, wd = wid & 1;
    const int g4 = lane >> 4, l16 = lane & 15;

    f32x4 acc[2][2] = {};

    for (int k0 = 0; k0 < B_; k0 += 64) {
        if (k0) __syncthreads();
        #pragma unroll
        for (int r = 0; r < 2; ++r) {
            int f = tid + r * 256;            // [0,512): 64 rows x 8 16B-units
            int row = f >> 3, u = f & 7;
            int su = (u ^ (row & 7)) * 8;
            int cc = c0 + row; if (cc > NC - 1) cc = NC - 1;
            *reinterpret_cast<uint4*>(&As[row * 64 + su]) =
                *reinterpret_cast<const uint4*>(&coefT[(size_t)cc * B_ + k0 + u * 8]);
            *reinterpret_cast<uint4*>(&Bs[row * 64 + su]) =
                *reinterpret_cast<const uint4*>(&xT[(size_t)(d0 + row) * B_ + k0 + u * 8]);
        }
        __syncthreads();
        #pragma unroll
        for (int kh = 0; kh < 2; ++kh) {
            bf16x8 af[2], bfr[2];
            int ubase = kh * 4 + g4;          // logical 16B unit = (kh*32 + g4*8) elems / 8
            #pragma unroll
            for (int fm = 0; fm < 2; ++fm) {
                int rowa = wc * 32 + fm * 16 + l16;
                af[fm] = *reinterpret_cast<const bf16x8*>(&As[rowa * 64 + ((ubase ^ (rowa & 7)) * 8)]);
                int rowb = wd * 32 + fm * 16 + l16;
                bfr[fm] = *reinterpret_cast<const bf16x8*>(&Bs[rowb * 64 + ((ubase ^ (rowb & 7)) * 8)]);
            }
            #pragma unroll
            for (int fm = 0; fm < 2; ++fm)
                #pragma unroll
                for (int fn = 0; fn < 2; ++fn)
                    acc[fm][fn] = __builtin_amdgcn_mfma_f32_16x16x32_bf16(af[fm], bfr[fn], acc[fm][fn], 0, 0, 0);
        }
    }

    #pragma unroll
    for (int fm = 0; fm < 2; ++fm) {
        #pragma unroll
        for (int r = 0; r < 4; ++r) {
            int c = c0 + wc * 32 + fm * 16 + g4 * 4 + r;
            if (c < NC) {
                float t = T[c];
                #pragma unroll
                for (int fn = 0; fn < 2; ++fn) {
                    int d = d0 + wd * 32 + fn * 16 + l16;
                    out[(size_t)c * D_ + d] = fmaf(t, w0[(size_t)c * D_ + d], acc[fm][fn][r]);
                }
            }
        }
    }
}

// fallback if ws is too small: direct forward recurrence, block per cell
__global__ __launch_bounds__(256) void k_update_fallback(const float* __restrict__ x, const float* __restrict__ w0,
                                                         const ull* __restrict__ bmu, const int* ep, const int* tp,
                                                         float* __restrict__ out) {
    int c = blockIdx.x;
    int d = threadIdx.x;
    int cy = c / W_, cx = c % W_;
    float lr, inv2r2;
    decay_params(ep, tp, lr, inv2r2);
    float acc = w0[(size_t)c * D_ + d];
    for (int i = 0; i < B_; ++i) {
        int idx = (int)(unsigned)(bmu[i] & 0xffffffffull);
        int by = idx / W_, bx = idx % W_;
        float dy = (float)(by - cy), dx = (float)(bx - cx);
        float a = lr * __expf(-(dy * dy + dx * dx) * inv2r2);
        acc = fmaf(a, x[(size_t)i * D_ + d] - acc, acc);
    }
    out[(size_t)c * D_ + d] = acc;
}

extern "C" void kernel_launch(void* const* d_in, const int* in_sizes, int n_in,
                              void* d_out, int out_size, void* d_ws, size_t ws_size,
                              hipStream_t stream) {
    const float* x = (const float*)d_in[0];
    const float* w = (const float*)d_in[1];
    const int* ep = (const int*)d_in[2];
    const int* tp = (const int*)d_in[3];
    float* out = (float*)d_out;

    char* ws = (char*)d_ws;
    ull* bmu      = (ull*)ws;                        // 1024 * 8B      @ 0
    float2* xy    = (float2*)(ws + 8192);            // 1024 * 8B      @ 8K
    float* T      = (float*)(ws + 16384);            // 10000 * 4B     @ 16K
    float* wnorm  = (float*)(ws + 65536);            // 10000 * 4B     @ 64K
    ushort_t* xT  = (ushort_t*)(ws + 131072);        // 256*1024*2B    @ 128K
    ushort_t* coefT = (ushort_t*)(ws + 655360);      // 10000*1024*2B  @ 640K
    size_t required = 655360 + (size_t)NC * B_ * 2;

    k_init<<<4, 256, 0, stream>>>(bmu);
    k_wnorm<<<NC / 4, 256, 0, stream>>>(w, wnorm);
    k_scores<<<dim3(B_ / 128, (NC + 127) / 128), 256, 0, stream>>>(x, w, wnorm, bmu);
    if (ws_size >= required) {
        k_decode<<<4, 256, 0, stream>>>(bmu, xy);
        k_xT<<<dim3(B_ / 64, D_ / 64), 256, 0, stream>>>(x, xT);
        k_scan<<<(NC * 8 + 255) / 256, 256, 0, stream>>>(xy, ep, tp, coefT, T);
        k_update<<<dim3((NC + 63) / 64, D_ / 64), 256, 0, stream>>>(coefT, xT, T, w, out);
    } else {
        k_update_fallback<<<NC, 256, 0, stream>>>(x, w, bmu, ep, tp, out);
    }
}

// Round 3
// 130.098 us; speedup vs baseline: 2.6487x; 1.1976x over previous
//
#include <hip/hip_runtime.h>
#include <hip/hip_fp16.h>

typedef unsigned long long ull;
typedef unsigned short ushort_t;
typedef short bf16x8 __attribute__((ext_vector_type(8)));
typedef float f32x4 __attribute__((ext_vector_type(4)));

#define NC 10000   // H*W cells
#define D_ 256     // input dim
#define B_ 1024    // batch
#define W_ 100     // grid width
#define LD 10240   // padded row stride for h
#define TAU 0.04f  // guard threshold (4*eps_score)
#define SHORTCAP 128

// monotonic float -> sortable uint mapping
__device__ __forceinline__ unsigned fkey(float f) {
    unsigned u = __float_as_uint(f);
    return (u & 0x80000000u) ? ~u : (u | 0x80000000u);
}
__device__ __forceinline__ float unfkey(unsigned k) {
    unsigned u = (k & 0x80000000u) ? (k ^ 0x80000000u) : ~k;
    return __uint_as_float(u);
}

// exact RNE float -> bf16 bits
__device__ __forceinline__ ushort_t f2bf(float f) {
    unsigned u = __float_as_uint(f);
    unsigned r = (u + 0x7fffu + ((u >> 16) & 1u)) >> 16;
    return (ushort_t)r;
}
__device__ __forceinline__ float bf2f(ushort_t b) {
    return __uint_as_float((unsigned)b << 16);
}

__device__ __forceinline__ void decay_params(const int* ep, const int* tp, float& lr, float& inv2r2) {
    double decay = 1.0 - (double)(*ep) / (double)(*tp);
    lr = (float)(0.5 * decay);
    float radius = (float)(50.0 * decay);
    inv2r2 = 1.0f / (2.0f * radius * radius);
}

// per cell (one wave): wnorm + hi/lo bf16 split of w
__global__ __launch_bounds__(256) void k_split_w(const float* __restrict__ w, ushort_t* __restrict__ wh,
                                                 ushort_t* __restrict__ wl, float* __restrict__ wnorm) {
    int cell = blockIdx.x * 4 + (threadIdx.x >> 6);
    int lane = threadIdx.x & 63;
    float4 v = *reinterpret_cast<const float4*>(&w[(size_t)cell * D_ + lane * 4]);
    float s = v.x * v.x + v.y * v.y + v.z * v.z + v.w * v.w;
    ushort_t hb[4], lb[4];
    float e[4] = {v.x, v.y, v.z, v.w};
    #pragma unroll
    for (int i = 0; i < 4; ++i) {
        hb[i] = f2bf(e[i]);
        lb[i] = f2bf(e[i] - bf2f(hb[i]));
    }
    *reinterpret_cast<uint2*>(&wh[(size_t)cell * D_ + lane * 4]) = *reinterpret_cast<uint2*>(hb);
    *reinterpret_cast<uint2*>(&wl[(size_t)cell * D_ + lane * 4]) = *reinterpret_cast<uint2*>(lb);
    #pragma unroll
    for (int off = 32; off; off >>= 1) s += __shfl_xor(s, off);
    if (lane == 0) wnorm[cell] = s;
}

// x -> xh, xl (row-major) + xhT (d-major transposed bf16 for update GEMM)
__global__ __launch_bounds__(256) void k_prep_x(const float* __restrict__ x, ushort_t* __restrict__ xh,
                                                ushort_t* __restrict__ xl, ushort_t* __restrict__ xhT) {
    __shared__ ushort_t tile[64][65];
    int b0 = blockIdx.x * 64, d0 = blockIdx.y * 64;
    int tid = threadIdx.x;
    #pragma unroll
    for (int r = 0; r < 16; ++r) {
        int idx = r * 256 + tid;
        int i = idx >> 6, j = idx & 63;       // i = b-local, j = d-local
        float v = x[(size_t)(b0 + i) * D_ + d0 + j];
        ushort_t hbit = f2bf(v);
        ushort_t lbit = f2bf(v - bf2f(hbit));
        xh[(size_t)(b0 + i) * D_ + d0 + j] = hbit;
        xl[(size_t)(b0 + i) * D_ + d0 + j] = lbit;
        tile[j][i] = hbit;
    }
    __syncthreads();
    #pragma unroll
    for (int r = 0; r < 2; ++r) {
        int f = r * 256 + tid;                // [0,512): 64 d-rows x 8 units
        int row = f >> 3, u = f & 7;
        ushort_t v[8];
        #pragma unroll
        for (int e = 0; e < 8; ++e) v[e] = tile[row][u * 8 + e];
        *reinterpret_cast<uint4*>(&xhT[(size_t)(d0 + row) * B_ + b0 + u * 8]) =
            *reinterpret_cast<uint4*>(v);
    }
}

// split-bf16 scores GEMM: h[b][c] = fp16( xh.wh + xh.wl + xl.wh )
// tile 128 cells x 128 batch, BK=64, 8 waves (2 cell x 4 batch), wave = 64x32
__global__ __launch_bounds__(512) void k_scores_mfma(const ushort_t* __restrict__ wh, const ushort_t* __restrict__ wl,
                                                     const ushort_t* __restrict__ xh, const ushort_t* __restrict__ xl,
                                                     __half* __restrict__ h) {
    __shared__ __align__(16) ushort_t As[128 * 64];  // cells x k
    __shared__ __align__(16) ushort_t Bs[128 * 64];  // batch x k
    const int tid = threadIdx.x;
    const int c0 = blockIdx.x * 128;
    const int b0 = blockIdx.y * 128;
    const int wid = tid >> 6, lane = tid & 63;
    const int wc = wid >> 2;           // 0..1 -> 64 cells
    const int wb = wid & 3;            // 0..3 -> 32 batch
    const int g4 = lane >> 4, l16 = lane & 15;

    f32x4 acc[4][2] = {};

    const ushort_t* aseg[3] = { wh, wl, wh };
    const ushort_t* bseg[3] = { xh, xh, xl };

    for (int seg = 0; seg < 3; ++seg) {
        const ushort_t* ap = aseg[seg];
        const ushort_t* bp = bseg[seg];
        for (int k0 = 0; k0 < D_; k0 += 64) {
            if (seg | k0) __syncthreads();
            #pragma unroll
            for (int r = 0; r < 2; ++r) {
                int f = tid + r * 512;        // [0,1024): 128 rows x 8 16B-units
                int row = f >> 3, u = f & 7;
                int su = (u ^ (row & 7)) * 8;
                int cc = c0 + row; if (cc > NC - 1) cc = NC - 1;
                *reinterpret_cast<uint4*>(&As[row * 64 + su]) =
                    *reinterpret_cast<const uint4*>(&ap[(size_t)cc * D_ + k0 + u * 8]);
                *reinterpret_cast<uint4*>(&Bs[row * 64 + su]) =
                    *reinterpret_cast<const uint4*>(&bp[(size_t)(b0 + row) * D_ + k0 + u * 8]);
            }
            __syncthreads();
            #pragma unroll
            for (int kh = 0; kh < 2; ++kh) {
                int ubase = kh * 4 + g4;
                bf16x8 bfr[2];
                #pragma unroll
                for (int fn = 0; fn < 2; ++fn) {
                    int rowb = wb * 32 + fn * 16 + l16;
                    bfr[fn] = *reinterpret_cast<const bf16x8*>(&Bs[rowb * 64 + ((ubase ^ (rowb & 7)) * 8)]);
                }
                #pragma unroll
                for (int fm = 0; fm < 4; ++fm) {
                    int rowa = wc * 64 + fm * 16 + l16;
                    bf16x8 af = *reinterpret_cast<const bf16x8*>(&As[rowa * 64 + ((ubase ^ (rowa & 7)) * 8)]);
                    #pragma unroll
                    for (int fn = 0; fn < 2; ++fn)
                        acc[fm][fn] = __builtin_amdgcn_mfma_f32_16x16x32_bf16(af, bfr[fn], acc[fm][fn], 0, 0, 0);
                }
            }
        }
    }
    // store h[b][c] fp16 (pad region c>=NC holds clamped-dup garbage; guard masks it)
    #pragma unroll
    for (int fm = 0; fm < 4; ++fm) {
        int cb = c0 + wc * 64 + fm * 16 + g4 * 4;
        #pragma unroll
        for (int fn = 0; fn < 2; ++fn) {
            int b = b0 + wb * 32 + fn * 16 + l16;
            __half hv[4];
            #pragma unroll
            for (int r = 0; r < 4; ++r) hv[r] = __float2half(acc[fm][fn][r]);
            *reinterpret_cast<uint2*>(&h[(size_t)b * LD + cb]) = *reinterpret_cast<uint2*>(hv);
        }
    }
}

__device__ __forceinline__ void merge2(ull& a1, ull& a2, ull c1, ull c2) {
    ull m1 = a1 < c1 ? a1 : c1;
    ull hi = a1 < c1 ? c1 : a1;
    ull lo2 = a2 < c2 ? a2 : c2;
    a2 = hi < lo2 ? hi : lo2;
    a1 = m1;
}

// per sample: argmin + runner-up over approx scores; flag tight gaps
__global__ __launch_bounds__(256) void k_guard(const __half* __restrict__ h, const float* __restrict__ wnorm,
                                               int* __restrict__ bmu_i, int* __restrict__ flag,
                                               ull* __restrict__ packed_fix) {
    __shared__ ull s1[8], s2[8];
    int b = blockIdx.x, tid = threadIdx.x;
    ull b1 = ~0ull, b2 = ~0ull;
    for (int ch = 0; ch < 10; ++ch) {
        int c = ch * 1024 + tid * 4;
        if (c < NC) {
            __half hv[4];
            *reinterpret_cast<uint2*>(hv) = *reinterpret_cast<const uint2*>(&h[(size_t)b * LD + c]);
            float4 wn = *reinterpret_cast<const float4*>(&wnorm[c]);
            float we[4] = {wn.x, wn.y, wn.z, wn.w};
            #pragma unroll
            for (int e = 0; e < 4; ++e) {
                float s = we[e] - 2.0f * (float)hv[e];
                ull p = ((ull)fkey(s) << 32) | (unsigned)(c + e);
                merge2(b1, b2, p, ~0ull);
            }
        }
    }
    #pragma unroll
    for (int off = 32; off; off >>= 1) {
        ull o1 = __shfl_xor(b1, off);
        ull o2 = __shfl_xor(b2, off);
        merge2(b1, b2, o1, o2);
    }
    int wv = tid >> 6;
    if ((tid & 63) == 0) { s1[wv] = b1; s2[wv] = b2; }
    __syncthreads();
    if (tid == 0) {
        #pragma unroll
        for (int k = 1; k < 4; ++k) merge2(b1, b2, s1[k], s2[k]);
        float f1 = unfkey((unsigned)(b1 >> 32));
        float f2 = unfkey((unsigned)(b2 >> 32));
        bmu_i[b] = (int)(unsigned)(b1 & 0xffffffffull);
        flag[b] = (f2 - f1 < TAU) ? 1 : 0;
        packed_fix[b] = ~0ull;
    }
}

// for flagged samples: shortlist cells near the min, recompute exact fp32, atomicMin
__global__ __launch_bounds__(256) void k_fix(const __half* __restrict__ h, const float* __restrict__ wnorm,
                                             const float* __restrict__ x, const float* __restrict__ w,
                                             const int* __restrict__ flag, const int* __restrict__ bmu_i,
                                             ull* __restrict__ packed_fix) {
    int b = blockIdx.x;
    if (!flag[b]) return;
    __shared__ int cnt;
    __shared__ int cand[SHORTCAP];
    __shared__ float smin_s;
    int tid = threadIdx.x;
    if (tid == 0) {
        cnt = 0;
        int c = bmu_i[b];
        smin_s = wnorm[c] - 2.0f * (float)h[(size_t)b * LD + c];
    }
    __syncthreads();
    float thr = smin_s + 0.02f;
    for (int ch = 0; ch < 10; ++ch) {
        int c = ch * 1024 + tid * 4;
        if (c < NC) {
            __half hv[4];
            *reinterpret_cast<uint2*>(hv) = *reinterpret_cast<const uint2*>(&h[(size_t)b * LD + c]);
            float4 wn = *reinterpret_cast<const float4*>(&wnorm[c]);
            float we[4] = {wn.x, wn.y, wn.z, wn.w};
            #pragma unroll
            for (int e = 0; e < 4; ++e) {
                float s = we[e] - 2.0f * (float)hv[e];
                if (s <= thr) {
                    int p = atomicAdd(&cnt, 1);
                    if (p < SHORTCAP) cand[p] = c + e;
                }
            }
        }
    }
    __syncthreads();
    int n = cnt;
    int wid = tid >> 6, lane = tid & 63;
    float4 xv = *reinterpret_cast<const float4*>(&x[(size_t)b * D_ + lane * 4]);
    ull best = ~0ull;
    if (n <= SHORTCAP) {
        for (int i = wid; i < n; i += 4) {
            int c = cand[i];
            float4 wv = *reinterpret_cast<const float4*>(&w[(size_t)c * D_ + lane * 4]);
            float p = wv.x * (wv.x - 2.0f * xv.x) + wv.y * (wv.y - 2.0f * xv.y)
                    + wv.z * (wv.z - 2.0f * xv.z) + wv.w * (wv.w - 2.0f * xv.w);
            #pragma unroll
            for (int off = 32; off; off >>= 1) p += __shfl_xor(p, off);
            if (lane == 0) {
                ull pk = ((ull)fkey(p) << 32) | (unsigned)c;
                best = pk < best ? pk : best;
            }
        }
    } else {  // pathological overflow: full exact scan (deterministic, ~never taken)
        for (int c = wid; c < NC; c += 4) {
            float4 wv = *reinterpret_cast<const float4*>(&w[(size_t)c * D_ + lane * 4]);
            float p = wv.x * (wv.x - 2.0f * xv.x) + wv.y * (wv.y - 2.0f * xv.y)
                    + wv.z * (wv.z - 2.0f * xv.z) + wv.w * (wv.w - 2.0f * xv.w);
            #pragma unroll
            for (int off = 32; off; off >>= 1) p += __shfl_xor(p, off);
            if (lane == 0) {
                ull pk = ((ull)fkey(p) << 32) | (unsigned)c;
                best = pk < best ? pk : best;
            }
        }
    }
    if (lane == 0 && best != ~0ull) atomicMin(&packed_fix[b], best);
}

__global__ void k_decode(const int* __restrict__ bmu_i, const int* __restrict__ flag,
                         const ull* __restrict__ packed_fix, float2* __restrict__ xy) {
    int i = blockIdx.x * 256 + threadIdx.x;
    if (i < B_) {
        int c = flag[i] ? (int)(unsigned)(packed_fix[i] & 0xffffffffull) : bmu_i[i];
        xy[i] = make_float2((float)(c / W_), (float)(c % W_));
    }
}

// chunked 2-pass suffix scan (unchanged from R2)
__global__ __launch_bounds__(256) void k_scan(const float2* __restrict__ xy, const int* __restrict__ ep,
                                              const int* __restrict__ tp, ushort_t* __restrict__ coefT,
                                              float* __restrict__ T) {
    int g = blockIdx.x * 256 + threadIdx.x;
    int c = g >> 3, t = g & 7;
    if (c >= NC) return;
    float cyf = (float)(c / W_), cxf = (float)(c % W_);
    float lr, inv2r2;
    decay_params(ep, tp, lr, inv2r2);
    int base = t * 128;

    float P = 1.0f;
    for (int i = base; i < base + 128; ++i) {
        float2 p = xy[i];
        float dy = p.x - cyf, dx = p.y - cxf;
        float a = lr * __expf(-(dy * dy + dx * dx) * inv2r2);
        P *= (1.0f - a);
    }
    int gbase = (threadIdx.x & 63) & ~7;
    float M = 1.0f;
    #pragma unroll
    for (int k = 1; k < 8; ++k) {
        float pk = __shfl(P, gbase + k, 64);
        if (k > t) M *= pk;
    }
    if (t == 0) T[c] = M * P;

    float s = M;
    for (int seg = 15; seg >= 0; --seg) {
        ushort_t buf[8];
        #pragma unroll
        for (int e = 7; e >= 0; --e) {
            int i = base + seg * 8 + e;
            float2 p = xy[i];
            float dy = p.x - cyf, dx = p.y - cxf;
            float a = lr * __expf(-(dy * dy + dx * dx) * inv2r2);
            buf[e] = f2bf(a * s);
            s *= (1.0f - a);
        }
        *reinterpret_cast<uint4*>(&coefT[(size_t)c * B_ + base + seg * 8]) =
            *reinterpret_cast<uint4*>(buf);
    }
}

// update GEMM via bf16 MFMA (unchanged from R2)
__global__ __launch_bounds__(256) void k_update(const ushort_t* __restrict__ coefT, const ushort_t* __restrict__ xhT,
                                                const float* __restrict__ T, const float* __restrict__ w0,
                                                float* __restrict__ out) {
    __shared__ __align__(16) ushort_t As[64 * 64];
    __shared__ __align__(16) ushort_t Bs[64 * 64];
    const int tid = threadIdx.x;
    const int c0 = blockIdx.x * 64, d0 = blockIdx.y * 64;
    const int wid = tid >> 6, lane = tid & 63;
    const int wc = wid >> 1, wd = wid & 1;
    const int g4 = lane >> 4, l16 = lane & 15;

    f32x4 acc[2][2] = {};

    for (int k0 = 0; k0 < B_; k0 += 64) {
        if (k0) __syncthreads();
        #pragma unroll
        for (int r = 0; r < 2; ++r) {
            int f = tid + r * 256;
            int row = f >> 3, u = f & 7;
            int su = (u ^ (row & 7)) * 8;
            int cc = c0 + row; if (cc > NC - 1) cc = NC - 1;
            *reinterpret_cast<uint4*>(&As[row * 64 + su]) =
                *reinterpret_cast<const uint4*>(&coefT[(size_t)cc * B_ + k0 + u * 8]);
            *reinterpret_cast<uint4*>(&Bs[row * 64 + su]) =
                *reinterpret_cast<const uint4*>(&xhT[(size_t)(d0 + row) * B_ + k0 + u * 8]);
        }
        __syncthreads();
        #pragma unroll
        for (int kh = 0; kh < 2; ++kh) {
            bf16x8 af[2], bfr[2];
            int ubase = kh * 4 + g4;
            #pragma unroll
            for (int fm = 0; fm < 2; ++fm) {
                int rowa = wc * 32 + fm * 16 + l16;
                af[fm] = *reinterpret_cast<const bf16x8*>(&As[rowa * 64 + ((ubase ^ (rowa & 7)) * 8)]);
                int rowb = wd * 32 + fm * 16 + l16;
                bfr[fm] = *reinterpret_cast<const bf16x8*>(&Bs[rowb * 64 + ((ubase ^ (rowb & 7)) * 8)]);
            }
            #pragma unroll
            for (int fm = 0; fm < 2; ++fm)
                #pragma unroll
                for (int fn = 0; fn < 2; ++fn)
                    acc[fm][fn] = __builtin_amdgcn_mfma_f32_16x16x32_bf16(af[fm], bfr[fn], acc[fm][fn], 0, 0, 0);
        }
    }

    #pragma unroll
    for (int fm = 0; fm < 2; ++fm) {
        #pragma unroll
        for (int r = 0; r < 4; ++r) {
            int c = c0 + wc * 32 + fm * 16 + g4 * 4 + r;
            if (c < NC) {
                float t = T[c];
                #pragma unroll
                for (int fn = 0; fn < 2; ++fn) {
                    int d = d0 + wd * 32 + fn * 16 + l16;
                    out[(size_t)c * D_ + d] = fmaf(t, w0[(size_t)c * D_ + d], acc[fm][fn][r]);
                }
            }
        }
    }
}

// ---------- tiny-ws fallback path ----------
__global__ void k_initfix(ull* packed_fix) {
    int i = blockIdx.x * 256 + threadIdx.x;
    if (i < B_) packed_fix[i] = ~0ull;
}
// exact fp32 BMU, standalone (slow, correct)
__global__ __launch_bounds__(256) void k_exact_bmu(const float* __restrict__ x, const float* __restrict__ w,
                                                   ull* __restrict__ packed_fix) {
    int b = blockIdx.x;
    int wid = threadIdx.x >> 6, lane = threadIdx.x & 63;
    float4 xv = *reinterpret_cast<const float4*>(&x[(size_t)b * D_ + lane * 4]);
    ull best = ~0ull;
    for (int c = wid; c < NC; c += 4) {
        float4 wv = *reinterpret_cast<const float4*>(&w[(size_t)c * D_ + lane * 4]);
        float p = wv.x * (wv.x - 2.0f * xv.x) + wv.y * (wv.y - 2.0f * xv.y)
                + wv.z * (wv.z - 2.0f * xv.z) + wv.w * (wv.w - 2.0f * xv.w);
        #pragma unroll
        for (int off = 32; off; off >>= 1) p += __shfl_xor(p, off);
        if (lane == 0) {
            ull pk = ((ull)fkey(p) << 32) | (unsigned)c;
            best = pk < best ? pk : best;
        }
    }
    if (lane == 0) atomicMin(&packed_fix[b], best);
}
__global__ void k_decode_force(const ull* __restrict__ packed_fix, float2* __restrict__ xy) {
    int i = blockIdx.x * 256 + threadIdx.x;
    if (i < B_) {
        int c = (int)(unsigned)(packed_fix[i] & 0xffffffffull);
        xy[i] = make_float2((float)(c / W_), (float)(c % W_));
    }
}
__global__ __launch_bounds__(256) void k_update_fallback(const float* __restrict__ x, const float* __restrict__ w0,
                                                         const float2* __restrict__ xy, const int* ep, const int* tp,
                                                         float* __restrict__ out) {
    int c = blockIdx.x;
    int d = threadIdx.x;
    float cyf = (float)(c / W_), cxf = (float)(c % W_);
    float lr, inv2r2;
    decay_params(ep, tp, lr, inv2r2);
    float acc = w0[(size_t)c * D_ + d];
    for (int i = 0; i < B_; ++i) {
        float2 p = xy[i];
        float dy = p.x - cyf, dx = p.y - cxf;
        float a = lr * __expf(-(dy * dy + dx * dx) * inv2r2);
        acc = fmaf(a, x[(size_t)i * D_ + d] - acc, acc);
    }
    out[(size_t)c * D_ + d] = acc;
}

extern "C" void kernel_launch(void* const* d_in, const int* in_sizes, int n_in,
                              void* d_out, int out_size, void* d_ws, size_t ws_size,
                              hipStream_t stream) {
    const float* x = (const float*)d_in[0];
    const float* w = (const float*)d_in[1];
    const int* ep = (const int*)d_in[2];
    const int* tp = (const int*)d_in[3];
    float* out = (float*)d_out;

    char* ws = (char*)d_ws;
    int* bmu_i      = (int*)ws;                      // 4KB   @ 0
    int* flag       = (int*)(ws + 4096);             // 4KB   @ 4K
    ull* packed_fix = (ull*)(ws + 8192);             // 8KB   @ 8K
    float2* xy      = (float2*)(ws + 16384);         // 8KB   @ 16K
    float* T        = (float*)(ws + 24576);          // 40KB  @ 24K
    float* wnorm    = (float*)(ws + 65536);          // 40KB  @ 64K
    ushort_t* xhT   = (ushort_t*)(ws + 131072);      // 512KB @ 128K
    ushort_t* xh    = (ushort_t*)(ws + 655360);      // 512KB
    ushort_t* xl    = (ushort_t*)(ws + 1179648);     // 512KB
    ushort_t* wh    = (ushort_t*)(ws + 1703936);     // 5MB
    ushort_t* wl    = (ushort_t*)(ws + 6823936);     // 5MB
    ushort_t* coefT = (ushort_t*)(ws + 1703936);     // 20MB (reuses wh/wl after BMU fixed)
    __half* h       = (__half*)(ws + 12582912);      // 21MB  @ 12MB
    size_t required = 12582912 + (size_t)B_ * LD * 2;  // 32MB

    if (ws_size >= required) {
        k_split_w<<<NC / 4, 256, 0, stream>>>(w, wh, wl, wnorm);
        k_prep_x<<<dim3(B_ / 64, D_ / 64), 256, 0, stream>>>(x, xh, xl, xhT);
        k_scores_mfma<<<dim3((NC + 127) / 128, B_ / 128), 512, 0, stream>>>(wh, wl, xh, xl, h);
        k_guard<<<B_, 256, 0, stream>>>(h, wnorm, bmu_i, flag, packed_fix);
        k_fix<<<B_, 256, 0, stream>>>(h, wnorm, x, w, flag, bmu_i, packed_fix);
        k_decode<<<4, 256, 0, stream>>>(bmu_i, flag, packed_fix, xy);
        k_scan<<<(NC * 8 + 255) / 256, 256, 0, stream>>>(xy, ep, tp, coefT, T);
        k_update<<<dim3((NC + 63) / 64, D_ / 64), 256, 0, stream>>>(coefT, xhT, T, w, out);
    } else {
        k_initfix<<<4, 256, 0, stream>>>(packed_fix);
        k_exact_bmu<<<B_, 256, 0, stream>>>(x, w, packed_fix);
        k_decode_force<<<4, 256, 0, stream>>>(packed_fix, xy);
        k_update_fallback<<<NC, 256, 0, stream>>>(x, w, xy, ep, tp, out);
    }
}

// Round 4
// 98.812 us; speedup vs baseline: 3.4873x; 1.3166x over previous
//
#include <hip/hip_runtime.h>
#include <hip/hip_fp16.h>

typedef unsigned long long ull;
typedef unsigned short ushort_t;
typedef unsigned int u32;
typedef short bf16x8 __attribute__((ext_vector_type(8)));
typedef _Float16 f16x8 __attribute__((ext_vector_type(8)));
typedef float f32x4 __attribute__((ext_vector_type(4)));

#define NC 10000   // H*W cells
#define D_ 256     // input dim
#define B_ 1024    // batch
#define W_ 100     // grid width
#define LD 10240   // padded row stride for h
#define TAU 0.15f  // guard threshold (>= 2*eps_max for fp16 path, generous)
#define FIXMARGIN 0.10f
#define SHORTCAP 128

// async global->LDS, 16B per lane; LDS dest = wave-uniform base + lane*16
__device__ __forceinline__ void gl_lds16(const void* g, void* l) {
    __builtin_amdgcn_global_load_lds(
        (const __attribute__((address_space(1))) u32*)g,
        (__attribute__((address_space(3))) u32*)l,
        16, 0, 0);
}

// monotonic float -> sortable uint mapping
__device__ __forceinline__ unsigned fkey(float f) {
    unsigned u = __float_as_uint(f);
    return (u & 0x80000000u) ? ~u : (u | 0x80000000u);
}
__device__ __forceinline__ float unfkey(unsigned k) {
    unsigned u = (k & 0x80000000u) ? (k ^ 0x80000000u) : ~k;
    return __uint_as_float(u);
}

// exact RNE float -> bf16 bits
__device__ __forceinline__ ushort_t f2bf(float f) {
    unsigned u = __float_as_uint(f);
    unsigned r = (u + 0x7fffu + ((u >> 16) & 1u)) >> 16;
    return (ushort_t)r;
}

__device__ __forceinline__ void decay_params(const int* ep, const int* tp, float& lr, float& inv2r2) {
    double decay = 1.0 - (double)(*ep) / (double)(*tp);
    lr = (float)(0.5 * decay);
    float radius = (float)(50.0 * decay);
    inv2r2 = 1.0f / (2.0f * radius * radius);
}

// per cell (one wave): wnorm + fp16 copy of w
__global__ __launch_bounds__(256) void k_split_w(const float* __restrict__ w, __half* __restrict__ wh,
                                                 float* __restrict__ wnorm) {
    int cell = blockIdx.x * 4 + (threadIdx.x >> 6);
    int lane = threadIdx.x & 63;
    float4 v = *reinterpret_cast<const float4*>(&w[(size_t)cell * D_ + lane * 4]);
    float s = v.x * v.x + v.y * v.y + v.z * v.z + v.w * v.w;
    __half hb[4];
    float e[4] = {v.x, v.y, v.z, v.w};
    #pragma unroll
    for (int i = 0; i < 4; ++i) hb[i] = __float2half(e[i]);
    *reinterpret_cast<uint2*>(&wh[(size_t)cell * D_ + lane * 4]) = *reinterpret_cast<uint2*>(hb);
    #pragma unroll
    for (int off = 32; off; off >>= 1) s += __shfl_xor(s, off);
    if (lane == 0) wnorm[cell] = s;
}

// x -> xh fp16 (row-major) + xhT bf16 (d-major transposed, for update GEMM)
__global__ __launch_bounds__(256) void k_prep_x(const float* __restrict__ x, __half* __restrict__ xh,
                                                ushort_t* __restrict__ xhT) {
    __shared__ ushort_t tile[64][65];
    int b0 = blockIdx.x * 64, d0 = blockIdx.y * 64;
    int tid = threadIdx.x;
    #pragma unroll
    for (int r = 0; r < 16; ++r) {
        int idx = r * 256 + tid;
        int i = idx >> 6, j = idx & 63;       // i = b-local, j = d-local
        float v = x[(size_t)(b0 + i) * D_ + d0 + j];
        xh[(size_t)(b0 + i) * D_ + d0 + j] = __float2half(v);
        tile[j][i] = f2bf(v);
    }
    __syncthreads();
    #pragma unroll
    for (int r = 0; r < 2; ++r) {
        int f = r * 256 + tid;                // [0,512): 64 d-rows x 8 units
        int row = f >> 3, u = f & 7;
        ushort_t v[8];
        #pragma unroll
        for (int e = 0; e < 8; ++e) v[e] = tile[row][u * 8 + e];
        *reinterpret_cast<uint4*>(&xhT[(size_t)(d0 + row) * B_ + b0 + u * 8]) =
            *reinterpret_cast<uint4*>(v);
    }
}

// fp16 scores GEMM: h[b][c] = fp16( xh . wh )
// tile 128 cells x 128 batch, BK=64, 8 waves (2 cell x 4 batch), wave = 64x32
// staging via global_load_lds (linear LDS dest) + pre-swizzled global source;
// reads use the same XOR involution (physical[row][p] = global[row][p^(row&7)])
__global__ __launch_bounds__(512) void k_scores_mfma(const __half* __restrict__ wh, const __half* __restrict__ xh,
                                                     __half* __restrict__ h) {
    __shared__ __align__(16) __half As[128 * 64];  // cells x k
    __shared__ __align__(16) __half Bs[128 * 64];  // batch x k
    const int tid = threadIdx.x;
    const int c0 = blockIdx.x * 128;
    const int b0 = blockIdx.y * 128;
    const int wid = tid >> 6, lane = tid & 63;
    const int wc = wid >> 2;           // 0..1 -> 64 cells
    const int wb = wid & 3;            // 0..3 -> 32 batch
    const int g4 = lane >> 4, l16 = lane & 15;

    f32x4 acc[4][2] = {};

    for (int k0 = 0; k0 < D_; k0 += 64) {
        if (k0) __syncthreads();
        #pragma unroll
        for (int r = 0; r < 2; ++r) {
            int f = tid + r * 512;        // [0,1024): 128 rows x 8 16B-units
            int row = f >> 3, u = f & 7;
            int ug = (u ^ (row & 7)) * 8;
            int cc = c0 + row; if (cc > NC - 1) cc = NC - 1;
            gl_lds16(&wh[(size_t)cc * D_ + k0 + ug], &As[(f & ~63) * 8]);
            gl_lds16(&xh[(size_t)(b0 + row) * D_ + k0 + ug], &Bs[(f & ~63) * 8]);
        }
        __syncthreads();
        #pragma unroll
        for (int kh = 0; kh < 2; ++kh) {
            int ubase = kh * 4 + g4;
            f16x8 bfr[2];
            #pragma unroll
            for (int fn = 0; fn < 2; ++fn) {
                int rowb = wb * 32 + fn * 16 + l16;
                bfr[fn] = *reinterpret_cast<const f16x8*>(&Bs[rowb * 64 + ((ubase ^ (rowb & 7)) * 8)]);
            }
            #pragma unroll
            for (int fm = 0; fm < 4; ++fm) {
                int rowa = wc * 64 + fm * 16 + l16;
                f16x8 af = *reinterpret_cast<const f16x8*>(&As[rowa * 64 + ((ubase ^ (rowa & 7)) * 8)]);
                #pragma unroll
                for (int fn = 0; fn < 2; ++fn)
                    acc[fm][fn] = __builtin_amdgcn_mfma_f32_16x16x32_f16(af, bfr[fn], acc[fm][fn], 0, 0, 0);
            }
        }
    }
    // store h[b][c] fp16 (pad region c>=NC holds clamped-dup garbage; guard masks it)
    #pragma unroll
    for (int fm = 0; fm < 4; ++fm) {
        int cb = c0 + wc * 64 + fm * 16 + g4 * 4;
        #pragma unroll
        for (int fn = 0; fn < 2; ++fn) {
            int b = b0 + wb * 32 + fn * 16 + l16;
            __half hv[4];
            #pragma unroll
            for (int r = 0; r < 4; ++r) hv[r] = __float2half(acc[fm][fn][r]);
            *reinterpret_cast<uint2*>(&h[(size_t)b * LD + cb]) = *reinterpret_cast<uint2*>(hv);
        }
    }
}

__device__ __forceinline__ void merge2(ull& a1, ull& a2, ull c1, ull c2) {
    ull m1 = a1 < c1 ? a1 : c1;
    ull hi = a1 < c1 ? c1 : a1;
    ull lo2 = a2 < c2 ? a2 : c2;
    a2 = hi < lo2 ? hi : lo2;
    a1 = m1;
}

// per sample: argmin + runner-up over approx scores; flag tight gaps
__global__ __launch_bounds__(256) void k_guard(const __half* __restrict__ h, const float* __restrict__ wnorm,
                                               int* __restrict__ bmu_i, int* __restrict__ flag,
                                               ull* __restrict__ packed_fix) {
    __shared__ ull s1[8], s2[8];
    int b = blockIdx.x, tid = threadIdx.x;
    ull b1 = ~0ull, b2 = ~0ull;
    for (int ch = 0; ch < 10; ++ch) {
        int c = ch * 1024 + tid * 4;
        if (c < NC) {
            __half hv[4];
            *reinterpret_cast<uint2*>(hv) = *reinterpret_cast<const uint2*>(&h[(size_t)b * LD + c]);
            float4 wn = *reinterpret_cast<const float4*>(&wnorm[c]);
            float we[4] = {wn.x, wn.y, wn.z, wn.w};
            #pragma unroll
            for (int e = 0; e < 4; ++e) {
                float s = we[e] - 2.0f * (float)hv[e];
                ull p = ((ull)fkey(s) << 32) | (unsigned)(c + e);
                merge2(b1, b2, p, ~0ull);
            }
        }
    }
    #pragma unroll
    for (int off = 32; off; off >>= 1) {
        ull o1 = __shfl_xor(b1, off);
        ull o2 = __shfl_xor(b2, off);
        merge2(b1, b2, o1, o2);
    }
    int wv = tid >> 6;
    if ((tid & 63) == 0) { s1[wv] = b1; s2[wv] = b2; }
    __syncthreads();
    if (tid == 0) {
        #pragma unroll
        for (int k = 1; k < 4; ++k) merge2(b1, b2, s1[k], s2[k]);
        float f1 = unfkey((unsigned)(b1 >> 32));
        float f2 = unfkey((unsigned)(b2 >> 32));
        bmu_i[b] = (int)(unsigned)(b1 & 0xffffffffull);
        flag[b] = (f2 - f1 < TAU) ? 1 : 0;
        packed_fix[b] = ~0ull;
    }
}

// for flagged samples: shortlist cells near the min, recompute exact fp32, atomicMin
__global__ __launch_bounds__(256) void k_fix(const __half* __restrict__ h, const float* __restrict__ wnorm,
                                             const float* __restrict__ x, const float* __restrict__ w,
                                             const int* __restrict__ flag, const int* __restrict__ bmu_i,
                                             ull* __restrict__ packed_fix) {
    int b = blockIdx.x;
    if (!flag[b]) return;
    __shared__ int cnt;
    __shared__ int cand[SHORTCAP];
    __shared__ float smin_s;
    int tid = threadIdx.x;
    if (tid == 0) {
        cnt = 0;
        int c = bmu_i[b];
        smin_s = wnorm[c] - 2.0f * (float)h[(size_t)b * LD + c];
    }
    __syncthreads();
    float thr = smin_s + FIXMARGIN;
    for (int ch = 0; ch < 10; ++ch) {
        int c = ch * 1024 + tid * 4;
        if (c < NC) {
            __half hv[4];
            *reinterpret_cast<uint2*>(hv) = *reinterpret_cast<const uint2*>(&h[(size_t)b * LD + c]);
            float4 wn = *reinterpret_cast<const float4*>(&wnorm[c]);
            float we[4] = {wn.x, wn.y, wn.z, wn.w};
            #pragma unroll
            for (int e = 0; e < 4; ++e) {
                float s = we[e] - 2.0f * (float)hv[e];
                if (s <= thr) {
                    int p = atomicAdd(&cnt, 1);
                    if (p < SHORTCAP) cand[p] = c + e;
                }
            }
        }
    }
    __syncthreads();
    int n = cnt;
    int wid = tid >> 6, lane = tid & 63;
    float4 xv = *reinterpret_cast<const float4*>(&x[(size_t)b * D_ + lane * 4]);
    ull best = ~0ull;
    if (n <= SHORTCAP) {
        for (int i = wid; i < n; i += 4) {
            int c = cand[i];
            float4 wv = *reinterpret_cast<const float4*>(&w[(size_t)c * D_ + lane * 4]);
            float p = wv.x * (wv.x - 2.0f * xv.x) + wv.y * (wv.y - 2.0f * xv.y)
                    + wv.z * (wv.z - 2.0f * xv.z) + wv.w * (wv.w - 2.0f * xv.w);
            #pragma unroll
            for (int off = 32; off; off >>= 1) p += __shfl_xor(p, off);
            if (lane == 0) {
                ull pk = ((ull)fkey(p) << 32) | (unsigned)c;
                best = pk < best ? pk : best;
            }
        }
    } else {  // pathological overflow: full exact scan (deterministic, ~never taken)
        for (int c = wid; c < NC; c += 4) {
            float4 wv = *reinterpret_cast<const float4*>(&w[(size_t)c * D_ + lane * 4]);
            float p = wv.x * (wv.x - 2.0f * xv.x) + wv.y * (wv.y - 2.0f * xv.y)
                    + wv.z * (wv.z - 2.0f * xv.z) + wv.w * (wv.w - 2.0f * xv.w);
            #pragma unroll
            for (int off = 32; off; off >>= 1) p += __shfl_xor(p, off);
            if (lane == 0) {
                ull pk = ((ull)fkey(p) << 32) | (unsigned)c;
                best = pk < best ? pk : best;
            }
        }
    }
    if (lane == 0 && best != ~0ull) atomicMin(&packed_fix[b], best);
}

__global__ void k_decode(const int* __restrict__ bmu_i, const int* __restrict__ flag,
                         const ull* __restrict__ packed_fix, int2* __restrict__ bxy) {
    int i = blockIdx.x * 256 + threadIdx.x;
    if (i < B_) {
        int c = flag[i] ? (int)(unsigned)(packed_fix[i] & 0xffffffffull) : bmu_i[i];
        bxy[i] = make_int2(c / W_, c % W_);
    }
}

// chunked 2-pass suffix scan with separable-Gaussian LDS table:
// a = lr * E[|by-cy|] * E[|bx-cx|],  E[k] = exp(-k^2 * inv2r2)
__global__ __launch_bounds__(256) void k_scan(const int2* __restrict__ bxy, const int* __restrict__ ep,
                                              const int* __restrict__ tp, ushort_t* __restrict__ coefT,
                                              float* __restrict__ T) {
    __shared__ float E[W_];
    float lr, inv2r2;
    decay_params(ep, tp, lr, inv2r2);
    if (threadIdx.x < W_) {
        float d = (float)threadIdx.x;
        E[threadIdx.x] = __expf(-d * d * inv2r2);
    }
    __syncthreads();

    int g = blockIdx.x * 256 + threadIdx.x;
    int c = g >> 3, t = g & 7;
    if (c >= NC) return;
    int cy = c / W_, cx = c % W_;
    int base = t * 128;

    // pass 1: chunk product P_t = prod_{i in chunk}(1 - a_i)
    float P = 1.0f;
    for (int i = base; i < base + 128; ++i) {
        int2 p = bxy[i];
        int dy = abs(p.x - cy), dx = abs(p.y - cx);
        float a = lr * E[dy] * E[dx];
        P *= (1.0f - a);
    }
    // M_t = prod_{t' > t} P_{t'} via shfl within the 8-lane group
    int gbase = (threadIdx.x & 63) & ~7;
    float M = 1.0f;
    #pragma unroll
    for (int k = 1; k < 8; ++k) {
        float pk = __shfl(P, gbase + k, 64);
        if (k > t) M *= pk;
    }
    if (t == 0) T[c] = M * P;

    // pass 2: descending, coef[i] = a_i * s
    float s = M;
    for (int seg = 15; seg >= 0; --seg) {
        ushort_t buf[8];
        #pragma unroll
        for (int e = 7; e >= 0; --e) {
            int i = base + seg * 8 + e;
            int2 p = bxy[i];
            int dy = abs(p.x - cy), dx = abs(p.y - cx);
            float a = lr * E[dy] * E[dx];
            buf[e] = f2bf(a * s);
            s *= (1.0f - a);
        }
        *reinterpret_cast<uint4*>(&coefT[(size_t)c * B_ + base + seg * 8]) =
            *reinterpret_cast<uint4*>(buf);
    }
}

// update GEMM via bf16 MFMA + global_load_lds staging (same swizzle involution)
__global__ __launch_bounds__(256) void k_update(const ushort_t* __restrict__ coefT, const ushort_t* __restrict__ xhT,
                                                const float* __restrict__ T, const float* __restrict__ w0,
                                                float* __restrict__ out) {
    __shared__ __align__(16) ushort_t As[64 * 64];
    __shared__ __align__(16) ushort_t Bs[64 * 64];
    const int tid = threadIdx.x;
    const int c0 = blockIdx.x * 64, d0 = blockIdx.y * 64;
    const int wid = tid >> 6, lane = tid & 63;
    const int wc = wid >> 1, wd = wid & 1;
    const int g4 = lane >> 4, l16 = lane & 15;

    f32x4 acc[2][2] = {};

    for (int k0 = 0; k0 < B_; k0 += 64) {
        if (k0) __syncthreads();
        #pragma unroll
        for (int r = 0; r < 2; ++r) {
            int f = tid + r * 256;        // [0,512): 64 rows x 8 16B-units
            int row = f >> 3, u = f & 7;
            int ug = (u ^ (row & 7)) * 8;
            int cc = c0 + row; if (cc > NC - 1) cc = NC - 1;
            gl_lds16(&coefT[(size_t)cc * B_ + k0 + ug], &As[(f & ~63) * 8]);
            gl_lds16(&xhT[(size_t)(d0 + row) * B_ + k0 + ug], &Bs[(f & ~63) * 8]);
        }
        __syncthreads();
        #pragma unroll
        for (int kh = 0; kh < 2; ++kh) {
            bf16x8 af[2], bfr[2];
            int ubase = kh * 4 + g4;
            #pragma unroll
            for (int fm = 0; fm < 2; ++fm) {
                int rowa = wc * 32 + fm * 16 + l16;
                af[fm] = *reinterpret_cast<const bf16x8*>(&As[rowa * 64 + ((ubase ^ (rowa & 7)) * 8)]);
                int rowb = wd * 32 + fm * 16 + l16;
                bfr[fm] = *reinterpret_cast<const bf16x8*>(&Bs[rowb * 64 + ((ubase ^ (rowb & 7)) * 8)]);
            }
            #pragma unroll
            for (int fm = 0; fm < 2; ++fm)
                #pragma unroll
                for (int fn = 0; fn < 2; ++fn)
                    acc[fm][fn] = __builtin_amdgcn_mfma_f32_16x16x32_bf16(af[fm], bfr[fn], acc[fm][fn], 0, 0, 0);
        }
    }

    #pragma unroll
    for (int fm = 0; fm < 2; ++fm) {
        #pragma unroll
        for (int r = 0; r < 4; ++r) {
            int c = c0 + wc * 32 + fm * 16 + g4 * 4 + r;
            if (c < NC) {
                float t = T[c];
                #pragma unroll
                for (int fn = 0; fn < 2; ++fn) {
                    int d = d0 + wd * 32 + fn * 16 + l16;
                    out[(size_t)c * D_ + d] = fmaf(t, w0[(size_t)c * D_ + d], acc[fm][fn][r]);
                }
            }
        }
    }
}

// ---------- tiny-ws fallback path ----------
__global__ void k_initfix(ull* packed_fix) {
    int i = blockIdx.x * 256 + threadIdx.x;
    if (i < B_) packed_fix[i] = ~0ull;
}
__global__ __launch_bounds__(256) void k_exact_bmu(const float* __restrict__ x, const float* __restrict__ w,
                                                   ull* __restrict__ packed_fix) {
    int b = blockIdx.x;
    int wid = threadIdx.x >> 6, lane = threadIdx.x & 63;
    float4 xv = *reinterpret_cast<const float4*>(&x[(size_t)b * D_ + lane * 4]);
    ull best = ~0ull;
    for (int c = wid; c < NC; c += 4) {
        float4 wv = *reinterpret_cast<const float4*>(&w[(size_t)c * D_ + lane * 4]);
        float p = wv.x * (wv.x - 2.0f * xv.x) + wv.y * (wv.y - 2.0f * xv.y)
                + wv.z * (wv.z - 2.0f * xv.z) + wv.w * (wv.w - 2.0f * xv.w);
        #pragma unroll
        for (int off = 32; off; off >>= 1) p += __shfl_xor(p, off);
        if (lane == 0) {
            ull pk = ((ull)fkey(p) << 32) | (unsigned)c;
            best = pk < best ? pk : best;
        }
    }
    if (lane == 0) atomicMin(&packed_fix[b], best);
}
__global__ void k_decode_force(const ull* __restrict__ packed_fix, float2* __restrict__ xy) {
    int i = blockIdx.x * 256 + threadIdx.x;
    if (i < B_) {
        int c = (int)(unsigned)(packed_fix[i] & 0xffffffffull);
        xy[i] = make_float2((float)(c / W_), (float)(c % W_));
    }
}
__global__ __launch_bounds__(256) void k_update_fallback(const float* __restrict__ x, const float* __restrict__ w0,
                                                         const float2* __restrict__ xy, const int* ep, const int* tp,
                                                         float* __restrict__ out) {
    int c = blockIdx.x;
    int d = threadIdx.x;
    float cyf = (float)(c / W_), cxf = (float)(c % W_);
    float lr, inv2r2;
    decay_params(ep, tp, lr, inv2r2);
    float acc = w0[(size_t)c * D_ + d];
    for (int i = 0; i < B_; ++i) {
        float2 p = xy[i];
        float dy = p.x - cyf, dx = p.y - cxf;
        float a = lr * __expf(-(dy * dy + dx * dx) * inv2r2);
        acc = fmaf(a, x[(size_t)i * D_ + d] - acc, acc);
    }
    out[(size_t)c * D_ + d] = acc;
}

extern "C" void kernel_launch(void* const* d_in, const int* in_sizes, int n_in,
                              void* d_out, int out_size, void* d_ws, size_t ws_size,
                              hipStream_t stream) {
    const float* x = (const float*)d_in[0];
    const float* w = (const float*)d_in[1];
    const int* ep = (const int*)d_in[2];
    const int* tp = (const int*)d_in[3];
    float* out = (float*)d_out;

    char* ws = (char*)d_ws;
    int* bmu_i      = (int*)ws;                      // 4KB    @ 0
    int* flag       = (int*)(ws + 4096);             // 4KB    @ 4K
    ull* packed_fix = (ull*)(ws + 8192);             // 8KB    @ 8K
    int2* bxy       = (int2*)(ws + 16384);           // 8KB    @ 16K
    float2* xyf     = (float2*)(ws + 16384);         // (fallback alias)
    float* T        = (float*)(ws + 24576);          // 40KB   @ 24K
    float* wnorm    = (float*)(ws + 65536);          // 40KB   @ 64K
    ushort_t* xhT   = (ushort_t*)(ws + 131072);      // 512KB  @ 128K
    __half* xh      = (__half*)(ws + 655360);        // 512KB
    __half* wh      = (__half*)(ws + 1179648);       // 5.12MB
    ushort_t* coefT = (ushort_t*)(ws + 6553600);     // 20.48MB
    __half* h       = (__half*)(ws + 27262976);      // 20.97MB @ 26MB
    size_t required = 27262976 + (size_t)B_ * LD * 2;  // ~48.2MB

    if (ws_size >= required) {
        k_split_w<<<NC / 4, 256, 0, stream>>>(w, wh, wnorm);
        k_prep_x<<<dim3(B_ / 64, D_ / 64), 256, 0, stream>>>(x, xh, xhT);
        k_scores_mfma<<<dim3((NC + 127) / 128, B_ / 128), 512, 0, stream>>>(wh, xh, h);
        k_guard<<<B_, 256, 0, stream>>>(h, wnorm, bmu_i, flag, packed_fix);
        k_fix<<<B_, 256, 0, stream>>>(h, wnorm, x, w, flag, bmu_i, packed_fix);
        k_decode<<<4, 256, 0, stream>>>(bmu_i, flag, packed_fix, bxy);
        k_scan<<<(NC * 8 + 255) / 256, 256, 0, stream>>>(bxy, ep, tp, coefT, T);
        k_update<<<dim3((NC + 63) / 64, D_ / 64), 256, 0, stream>>>(coefT, xhT, T, w, out);
    } else {
        k_initfix<<<4, 256, 0, stream>>>(packed_fix);
        k_exact_bmu<<<B_, 256, 0, stream>>>(x, w, packed_fix);
        k_decode_force<<<4, 256, 0, stream>>>(packed_fix, xyf);
        k_update_fallback<<<NC, 256, 0, stream>>>(x, w, xyf, ep, tp, out);
    }
}

// Round 5
// 92.217 us; speedup vs baseline: 3.7367x; 1.0715x over previous
//
#include <hip/hip_runtime.h>
#include <hip/hip_fp16.h>

typedef unsigned long long ull;
typedef unsigned short ushort_t;
typedef unsigned int u32;
typedef short bf16x8 __attribute__((ext_vector_type(8)));
typedef _Float16 f16x8 __attribute__((ext_vector_type(8)));
typedef float f32x4 __attribute__((ext_vector_type(4)));

#define NC 10000   // H*W cells
#define D_ 256     // input dim
#define B_ 1024    // batch
#define W_ 100     // grid width
#define LD 10240   // padded row stride for h
#define FIXMARGIN 0.06f  // >= 2*eps_score(fp16 mfma) + fp16 h-store rounding
#define SHORTCAP 128

// async global->LDS, 16B per lane; LDS dest = wave-uniform base + lane*16
__device__ __forceinline__ void gl_lds16(const void* g, void* l) {
    __builtin_amdgcn_global_load_lds(
        (const __attribute__((address_space(1))) u32*)g,
        (__attribute__((address_space(3))) u32*)l,
        16, 0, 0);
}

// bijective XCD-chunk swizzle (m204): contiguous logical tiles per XCD
__device__ __forceinline__ int xcd_swz(int orig, int nwg) {
    int q = nwg >> 3, r = nwg & 7;
    int xcd = orig & 7, off = orig >> 3;
    return (xcd < r ? xcd * (q + 1) : r * (q + 1) + (xcd - r) * q) + off;
}

// monotonic float -> sortable uint mapping
__device__ __forceinline__ unsigned fkey(float f) {
    unsigned u = __float_as_uint(f);
    return (u & 0x80000000u) ? ~u : (u | 0x80000000u);
}
__device__ __forceinline__ float unfkey(unsigned k) {
    unsigned u = (k & 0x80000000u) ? (k ^ 0x80000000u) : ~k;
    return __uint_as_float(u);
}

// exact RNE float -> bf16 bits
__device__ __forceinline__ ushort_t f2bf(float f) {
    unsigned u = __float_as_uint(f);
    unsigned r = (u + 0x7fffu + ((u >> 16) & 1u)) >> 16;
    return (ushort_t)r;
}

__device__ __forceinline__ void decay_params(const int* ep, const int* tp, float& lr, float& inv2r2) {
    double decay = 1.0 - (double)(*ep) / (double)(*tp);
    lr = (float)(0.5 * decay);
    float radius = (float)(50.0 * decay);
    inv2r2 = 1.0f / (2.0f * radius * radius);
}

// init pk1 + pad wnorm[NC..NC+128) with +inf (phantom tile rows read it)
__global__ void k_init(ull* pk1, float* wnorm) {
    int i = blockIdx.x * 256 + threadIdx.x;
    if (i < B_) pk1[i] = ~0ull;
    else if (i < B_ + 128) wnorm[NC + (i - B_)] = __builtin_inff();
}

// per cell (one wave): wnorm + fp16 copy of w
__global__ __launch_bounds__(256) void k_split_w(const float* __restrict__ w, __half* __restrict__ wh,
                                                 float* __restrict__ wnorm) {
    int cell = blockIdx.x * 4 + (threadIdx.x >> 6);
    int lane = threadIdx.x & 63;
    float4 v = *reinterpret_cast<const float4*>(&w[(size_t)cell * D_ + lane * 4]);
    float s = v.x * v.x + v.y * v.y + v.z * v.z + v.w * v.w;
    __half hb[4];
    float e[4] = {v.x, v.y, v.z, v.w};
    #pragma unroll
    for (int i = 0; i < 4; ++i) hb[i] = __float2half(e[i]);
    *reinterpret_cast<uint2*>(&wh[(size_t)cell * D_ + lane * 4]) = *reinterpret_cast<uint2*>(hb);
    #pragma unroll
    for (int off = 32; off; off >>= 1) s += __shfl_xor(s, off);
    if (lane == 0) wnorm[cell] = s;
}

// x -> xh fp16 (row-major) + xhT bf16 (d-major transposed, for update GEMM)
__global__ __launch_bounds__(256) void k_prep_x(const float* __restrict__ x, __half* __restrict__ xh,
                                                ushort_t* __restrict__ xhT) {
    __shared__ ushort_t tile[64][65];
    int b0 = blockIdx.x * 64, d0 = blockIdx.y * 64;
    int tid = threadIdx.x;
    #pragma unroll
    for (int r = 0; r < 16; ++r) {
        int idx = r * 256 + tid;
        int i = idx >> 6, j = idx & 63;       // i = b-local, j = d-local
        float v = x[(size_t)(b0 + i) * D_ + d0 + j];
        xh[(size_t)(b0 + i) * D_ + d0 + j] = __float2half(v);
        tile[j][i] = f2bf(v);
    }
    __syncthreads();
    #pragma unroll
    for (int r = 0; r < 2; ++r) {
        int f = r * 256 + tid;                // [0,512): 64 d-rows x 8 units
        int row = f >> 3, u = f & 7;
        ushort_t v[8];
        #pragma unroll
        for (int e = 0; e < 8; ++e) v[e] = tile[row][u * 8 + e];
        *reinterpret_cast<uint4*>(&xhT[(size_t)(d0 + row) * B_ + b0 + u * 8]) =
            *reinterpret_cast<uint4*>(v);
    }
}

// fp16 scores GEMM + fused per-sample min1: h[b][c] = fp16(xh.wh);
// pk1[b] = atomicMin packed (fkey(wnorm - 2*dot) << 32 | cell)
// grid: x = 8 b-tiles (fast), y = 79 c-tiles; XCD-swizzled so b-tile sharers co-reside
__global__ __launch_bounds__(512) void k_scores_mfma(const __half* __restrict__ wh, const __half* __restrict__ xh,
                                                     const float* __restrict__ wnorm, __half* __restrict__ h,
                                                     ull* __restrict__ pk1) {
    __shared__ __align__(16) __half As[128 * 64];  // cells x k
    __shared__ __align__(16) __half Bs[128 * 64];  // batch x k
    const int tid = threadIdx.x;
    int orig = blockIdx.y * gridDim.x + blockIdx.x;
    int wgid = xcd_swz(orig, 8 * 79);
    const int b0 = (wgid & 7) * 128;
    const int c0 = (wgid >> 3) * 128;
    const int wid = tid >> 6, lane = tid & 63;
    const int wc = wid >> 2;           // 0..1 -> 64 cells
    const int wb = wid & 3;            // 0..3 -> 32 batch
    const int g4 = lane >> 4, l16 = lane & 15;

    f32x4 acc[4][2] = {};

    for (int k0 = 0; k0 < D_; k0 += 64) {
        if (k0) __syncthreads();
        #pragma unroll
        for (int r = 0; r < 2; ++r) {
            int f = tid + r * 512;        // [0,1024): 128 rows x 8 16B-units
            int row = f >> 3, u = f & 7;
            int ug = (u ^ (row & 7)) * 8;
            int cc = c0 + row; if (cc > NC - 1) cc = NC - 1;
            gl_lds16(&wh[(size_t)cc * D_ + k0 + ug], &As[(f & ~63) * 8]);
            gl_lds16(&xh[(size_t)(b0 + row) * D_ + k0 + ug], &Bs[(f & ~63) * 8]);
        }
        __syncthreads();
        #pragma unroll
        for (int kh = 0; kh < 2; ++kh) {
            int ubase = kh * 4 + g4;
            f16x8 bfr[2];
            #pragma unroll
            for (int fn = 0; fn < 2; ++fn) {
                int rowb = wb * 32 + fn * 16 + l16;
                bfr[fn] = *reinterpret_cast<const f16x8*>(&Bs[rowb * 64 + ((ubase ^ (rowb & 7)) * 8)]);
            }
            #pragma unroll
            for (int fm = 0; fm < 4; ++fm) {
                int rowa = wc * 64 + fm * 16 + l16;
                f16x8 af = *reinterpret_cast<const f16x8*>(&As[rowa * 64 + ((ubase ^ (rowa & 7)) * 8)]);
                #pragma unroll
                for (int fn = 0; fn < 2; ++fn)
                    acc[fm][fn] = __builtin_amdgcn_mfma_f32_16x16x32_f16(af, bfr[fn], acc[fm][fn], 0, 0, 0);
            }
        }
    }

    // store h (dot, fp16) — k_fix shortlists from it
    #pragma unroll
    for (int fm = 0; fm < 4; ++fm) {
        int cb = c0 + wc * 64 + fm * 16 + g4 * 4;
        #pragma unroll
        for (int fn = 0; fn < 2; ++fn) {
            int b = b0 + wb * 32 + fn * 16 + l16;
            __half hv[4];
            #pragma unroll
            for (int r = 0; r < 4; ++r) hv[r] = __float2half(acc[fm][fn][r]);
            *reinterpret_cast<uint2*>(&h[(size_t)b * LD + cb]) = *reinterpret_cast<uint2*>(hv);
        }
    }

    // fused min1: per-lane reduce over fm,r; shfl across g4; one atomic per column
    ull best[2] = {~0ull, ~0ull};
    #pragma unroll
    for (int fm = 0; fm < 4; ++fm) {
        int cb = c0 + wc * 64 + fm * 16 + g4 * 4;
        float4 wn4 = *reinterpret_cast<const float4*>(&wnorm[cb]);  // padded +inf for cb>=NC
        float wna[4] = {wn4.x, wn4.y, wn4.z, wn4.w};
        #pragma unroll
        for (int fn = 0; fn < 2; ++fn)
            #pragma unroll
            for (int r = 0; r < 4; ++r) {
                float s = wna[r] - 2.0f * acc[fm][fn][r];
                ull p = ((ull)fkey(s) << 32) | (unsigned)(cb + r);
                if (p < best[fn]) best[fn] = p;
            }
    }
    #pragma unroll
    for (int fn = 0; fn < 2; ++fn) {
        ull o = __shfl_xor(best[fn], 16); best[fn] = o < best[fn] ? o : best[fn];
        o = __shfl_xor(best[fn], 32);     best[fn] = o < best[fn] ? o : best[fn];
    }
    if (g4 == 0) {
        atomicMin(&pk1[b0 + wb * 32 + l16], best[0]);
        atomicMin(&pk1[b0 + wb * 32 + 16 + l16], best[1]);
    }
}

// always-on fix: shortlist cells within FIXMARGIN of approx min, exact fp32 dots,
// block-local reduce, write bxy directly (no guard/decode kernels)
__global__ __launch_bounds__(256) void k_fix(const __half* __restrict__ h, const float* __restrict__ wnorm,
                                             const float* __restrict__ x, const float* __restrict__ w,
                                             const ull* __restrict__ pk1, int2* __restrict__ bxy) {
    __shared__ int cnt;
    __shared__ int cand[SHORTCAP];
    __shared__ ull sbest[4];
    int b = blockIdx.x, tid = threadIdx.x;
    if (tid == 0) cnt = 0;
    __syncthreads();
    float thr = unfkey((unsigned)(pk1[b] >> 32)) + FIXMARGIN;
    for (int ch = 0; ch < 10; ++ch) {
        int c = ch * 1024 + tid * 4;
        if (c < NC) {
            __half hv[4];
            *reinterpret_cast<uint2*>(hv) = *reinterpret_cast<const uint2*>(&h[(size_t)b * LD + c]);
            float4 wn = *reinterpret_cast<const float4*>(&wnorm[c]);
            float we[4] = {wn.x, wn.y, wn.z, wn.w};
            #pragma unroll
            for (int e = 0; e < 4; ++e) {
                float s = we[e] - 2.0f * (float)hv[e];
                if (s <= thr) {
                    int p = atomicAdd(&cnt, 1);
                    if (p < SHORTCAP) cand[p] = c + e;
                }
            }
        }
    }
    __syncthreads();
    int n = cnt;
    int wid = tid >> 6, lane = tid & 63;
    float4 xv = *reinterpret_cast<const float4*>(&x[(size_t)b * D_ + lane * 4]);
    ull best = ~0ull;
    if (n <= SHORTCAP) {
        for (int i = wid; i < n; i += 4) {
            int c = cand[i];
            float4 wv = *reinterpret_cast<const float4*>(&w[(size_t)c * D_ + lane * 4]);
            float p = wv.x * (wv.x - 2.0f * xv.x) + wv.y * (wv.y - 2.0f * xv.y)
                    + wv.z * (wv.z - 2.0f * xv.z) + wv.w * (wv.w - 2.0f * xv.w);
            #pragma unroll
            for (int off = 32; off; off >>= 1) p += __shfl_xor(p, off);
            if (lane == 0) {
                ull pk = ((ull)fkey(p) << 32) | (unsigned)c;
                best = pk < best ? pk : best;
            }
        }
    } else {  // pathological overflow: full exact scan (deterministic, ~never taken)
        for (int c = wid; c < NC; c += 4) {
            float4 wv = *reinterpret_cast<const float4*>(&w[(size_t)c * D_ + lane * 4]);
            float p = wv.x * (wv.x - 2.0f * xv.x) + wv.y * (wv.y - 2.0f * xv.y)
                    + wv.z * (wv.z - 2.0f * xv.z) + wv.w * (wv.w - 2.0f * xv.w);
            #pragma unroll
            for (int off = 32; off; off >>= 1) p += __shfl_xor(p, off);
            if (lane == 0) {
                ull pk = ((ull)fkey(p) << 32) | (unsigned)c;
                best = pk < best ? pk : best;
            }
        }
    }
    if (lane == 0) sbest[wid] = best;
    __syncthreads();
    if (tid == 0) {
        ull bb = sbest[0];
        #pragma unroll
        for (int k = 1; k < 4; ++k) bb = sbest[k] < bb ? sbest[k] : bb;
        int c = (int)(unsigned)(bb & 0xffffffffull);
        bxy[b] = make_int2(c / W_, c % W_);
    }
}

// chunked 2-pass suffix scan with separable-Gaussian LDS table
__global__ __launch_bounds__(256) void k_scan(const int2* __restrict__ bxy, const int* __restrict__ ep,
                                              const int* __restrict__ tp, ushort_t* __restrict__ coefT,
                                              float* __restrict__ T) {
    __shared__ float E[W_];
    float lr, inv2r2;
    decay_params(ep, tp, lr, inv2r2);
    if (threadIdx.x < W_) {
        float d = (float)threadIdx.x;
        E[threadIdx.x] = __expf(-d * d * inv2r2);
    }
    __syncthreads();

    int g = blockIdx.x * 256 + threadIdx.x;
    int c = g >> 3, t = g & 7;
    if (c >= NC) return;
    int cy = c / W_, cx = c % W_;
    int base = t * 128;

    float P = 1.0f;
    for (int i = base; i < base + 128; ++i) {
        int2 p = bxy[i];
        int dy = abs(p.x - cy), dx = abs(p.y - cx);
        float a = lr * E[dy] * E[dx];
        P *= (1.0f - a);
    }
    int gbase = (threadIdx.x & 63) & ~7;
    float M = 1.0f;
    #pragma unroll
    for (int k = 1; k < 8; ++k) {
        float pk = __shfl(P, gbase + k, 64);
        if (k > t) M *= pk;
    }
    if (t == 0) T[c] = M * P;

    float s = M;
    for (int seg = 15; seg >= 0; --seg) {
        ushort_t buf[8];
        #pragma unroll
        for (int e = 7; e >= 0; --e) {
            int i = base + seg * 8 + e;
            int2 p = bxy[i];
            int dy = abs(p.x - cy), dx = abs(p.y - cx);
            float a = lr * E[dy] * E[dx];
            buf[e] = f2bf(a * s);
            s *= (1.0f - a);
        }
        *reinterpret_cast<uint4*>(&coefT[(size_t)c * B_ + base + seg * 8]) =
            *reinterpret_cast<uint4*>(buf);
    }
}

// update GEMM via bf16 MFMA + global_load_lds staging
// grid: x = 4 d-tiles (fast), y = 157 c-tiles; XCD-swizzled so coefT sharers co-reside
__global__ __launch_bounds__(256) void k_update(const ushort_t* __restrict__ coefT, const ushort_t* __restrict__ xhT,
                                                const float* __restrict__ T, const float* __restrict__ w0,
                                                float* __restrict__ out) {
    __shared__ __align__(16) ushort_t As[64 * 64];
    __shared__ __align__(16) ushort_t Bs[64 * 64];
    const int tid = threadIdx.x;
    int orig = blockIdx.y * gridDim.x + blockIdx.x;
    int wgid = xcd_swz(orig, 4 * 157);
    const int d0 = (wgid & 3) * 64;
    const int c0 = (wgid >> 2) * 64;
    const int wid = tid >> 6, lane = tid & 63;
    const int wc = wid >> 1, wd = wid & 1;
    const int g4 = lane >> 4, l16 = lane & 15;

    f32x4 acc[2][2] = {};

    for (int k0 = 0; k0 < B_; k0 += 64) {
        if (k0) __syncthreads();
        #pragma unroll
        for (int r = 0; r < 2; ++r) {
            int f = tid + r * 256;        // [0,512): 64 rows x 8 16B-units
            int row = f >> 3, u = f & 7;
            int ug = (u ^ (row & 7)) * 8;
            int cc = c0 + row; if (cc > NC - 1) cc = NC - 1;
            gl_lds16(&coefT[(size_t)cc * B_ + k0 + ug], &As[(f & ~63) * 8]);
            gl_lds16(&xhT[(size_t)(d0 + row) * B_ + k0 + ug], &Bs[(f & ~63) * 8]);
        }
        __syncthreads();
        #pragma unroll
        for (int kh = 0; kh < 2; ++kh) {
            bf16x8 af[2], bfr[2];
            int ubase = kh * 4 + g4;
            #pragma unroll
            for (int fm = 0; fm < 2; ++fm) {
                int rowa = wc * 32 + fm * 16 + l16;
                af[fm] = *reinterpret_cast<const bf16x8*>(&As[rowa * 64 + ((ubase ^ (rowa & 7)) * 8)]);
                int rowb = wd * 32 + fm * 16 + l16;
                bfr[fm] = *reinterpret_cast<const bf16x8*>(&Bs[rowb * 64 + ((ubase ^ (rowb & 7)) * 8)]);
            }
            #pragma unroll
            for (int fm = 0; fm < 2; ++fm)
                #pragma unroll
                for (int fn = 0; fn < 2; ++fn)
                    acc[fm][fn] = __builtin_amdgcn_mfma_f32_16x16x32_bf16(af[fm], bfr[fn], acc[fm][fn], 0, 0, 0);
        }
    }

    #pragma unroll
    for (int fm = 0; fm < 2; ++fm) {
        #pragma unroll
        for (int r = 0; r < 4; ++r) {
            int c = c0 + wc * 32 + fm * 16 + g4 * 4 + r;
            if (c < NC) {
                float t = T[c];
                #pragma unroll
                for (int fn = 0; fn < 2; ++fn) {
                    int d = d0 + wd * 32 + fn * 16 + l16;
                    out[(size_t)c * D_ + d] = fmaf(t, w0[(size_t)c * D_ + d], acc[fm][fn][r]);
                }
            }
        }
    }
}

// ---------- tiny-ws fallback path ----------
__global__ void k_initfix(ull* packed_fix) {
    int i = blockIdx.x * 256 + threadIdx.x;
    if (i < B_) packed_fix[i] = ~0ull;
}
__global__ __launch_bounds__(256) void k_exact_bmu(const float* __restrict__ x, const float* __restrict__ w,
                                                   ull* __restrict__ packed_fix) {
    int b = blockIdx.x;
    int wid = threadIdx.x >> 6, lane = threadIdx.x & 63;
    float4 xv = *reinterpret_cast<const float4*>(&x[(size_t)b * D_ + lane * 4]);
    ull best = ~0ull;
    for (int c = wid; c < NC; c += 4) {
        float4 wv = *reinterpret_cast<const float4*>(&w[(size_t)c * D_ + lane * 4]);
        float p = wv.x * (wv.x - 2.0f * xv.x) + wv.y * (wv.y - 2.0f * xv.y)
                + wv.z * (wv.z - 2.0f * xv.z) + wv.w * (wv.w - 2.0f * xv.w);
        #pragma unroll
        for (int off = 32; off; off >>= 1) p += __shfl_xor(p, off);
        if (lane == 0) {
            ull pk = ((ull)fkey(p) << 32) | (unsigned)c;
            best = pk < best ? pk : best;
        }
    }
    if (lane == 0) atomicMin(&packed_fix[b], best);
}
__global__ void k_decode_force(const ull* __restrict__ packed_fix, float2* __restrict__ xy) {
    int i = blockIdx.x * 256 + threadIdx.x;
    if (i < B_) {
        int c = (int)(unsigned)(packed_fix[i] & 0xffffffffull);
        xy[i] = make_float2((float)(c / W_), (float)(c % W_));
    }
}
__global__ __launch_bounds__(256) void k_update_fallback(const float* __restrict__ x, const float* __restrict__ w0,
                                                         const float2* __restrict__ xy, const int* ep, const int* tp,
                                                         float* __restrict__ out) {
    int c = blockIdx.x;
    int d = threadIdx.x;
    float cyf = (float)(c / W_), cxf = (float)(c % W_);
    float lr, inv2r2;
    decay_params(ep, tp, lr, inv2r2);
    float acc = w0[(size_t)c * D_ + d];
    for (int i = 0; i < B_; ++i) {
        float2 p = xy[i];
        float dy = p.x - cyf, dx = p.y - cxf;
        float a = lr * __expf(-(dy * dy + dx * dx) * inv2r2);
        acc = fmaf(a, x[(size_t)i * D_ + d] - acc, acc);
    }
    out[(size_t)c * D_ + d] = acc;
}

extern "C" void kernel_launch(void* const* d_in, const int* in_sizes, int n_in,
                              void* d_out, int out_size, void* d_ws, size_t ws_size,
                              hipStream_t stream) {
    const float* x = (const float*)d_in[0];
    const float* w = (const float*)d_in[1];
    const int* ep = (const int*)d_in[2];
    const int* tp = (const int*)d_in[3];
    float* out = (float*)d_out;

    char* ws = (char*)d_ws;
    ull* pk1        = (ull*)ws;                      // 8KB    @ 0
    int2* bxy       = (int2*)(ws + 16384);           // 8KB    @ 16K
    float2* xyf     = (float2*)(ws + 16384);         // (fallback alias)
    float* T        = (float*)(ws + 24576);          // 40KB   @ 24K
    float* wnorm    = (float*)(ws + 65536);          // 40.5KB @ 64K (padded +128)
    ushort_t* xhT   = (ushort_t*)(ws + 131072);      // 512KB  @ 128K
    __half* xh      = (__half*)(ws + 655360);        // 512KB
    __half* wh      = (__half*)(ws + 1179648);       // 5.12MB
    ushort_t* coefT = (ushort_t*)(ws + 6553600);     // 20.48MB
    __half* h       = (__half*)(ws + 27262976);      // 20.97MB @ 26MB
    size_t required = 27262976 + (size_t)B_ * LD * 2;  // ~48.2MB

    if (ws_size >= required) {
        k_init<<<5, 256, 0, stream>>>(pk1, wnorm);
        k_split_w<<<NC / 4, 256, 0, stream>>>(w, wh, wnorm);
        k_prep_x<<<dim3(B_ / 64, D_ / 64), 256, 0, stream>>>(x, xh, xhT);
        k_scores_mfma<<<dim3(B_ / 128, (NC + 127) / 128), 512, 0, stream>>>(wh, xh, wnorm, h, pk1);
        k_fix<<<B_, 256, 0, stream>>>(h, wnorm, x, w, pk1, bxy);
        k_scan<<<(NC * 8 + 255) / 256, 256, 0, stream>>>(bxy, ep, tp, coefT, T);
        k_update<<<dim3(D_ / 64, (NC + 63) / 64), 256, 0, stream>>>(coefT, xhT, T, w, out);
    } else {
        k_initfix<<<4, 256, 0, stream>>>(pk1);
        k_exact_bmu<<<B_, 256, 0, stream>>>(x, w, pk1);
        k_decode_force<<<4, 256, 0, stream>>>(pk1, xyf);
        k_update_fallback<<<NC, 256, 0, stream>>>(x, w, xyf, ep, tp, out);
    }
}